// Round 6
// baseline (412.978 us; speedup 1.0000x reference)
//
#include <hip/hip_runtime.h>

typedef unsigned short u16;
typedef __attribute__((ext_vector_type(4))) float f32x4;
typedef _Float16 f16x8 __attribute__((ext_vector_type(8)));
typedef __attribute__((ext_vector_type(4))) u16   u16x4;
typedef __attribute__((ext_vector_type(8))) u16   u16x8;

#define DEV static __device__ __forceinline__

constexpr int Ll = 4096;

DEV float h2f(u16 v) { _Float16 h; __builtin_memcpy(&h, &v, 2); return (float)h; }
DEV u16 f2h(float f) { _Float16 h = (_Float16)f; u16 u; __builtin_memcpy(&u, &h, 2); return u; }

DEV f32x4 mfma16h(f16x8 a, f16x8 b, f32x4 c) {
    return __builtin_amdgcn_mfma_f32_16x16x32_f16(a, b, c, 0, 0, 0);
}

#if defined(__has_builtin)
#if __has_builtin(__builtin_amdgcn_global_load_lds)
#define HAS_GLLDS 1
#endif
#endif
#ifndef HAS_GLLDS
#define HAS_GLLDS 0
#endif

// Stage a [128][32] u16 tile (8KB) into DST with XOR-swizzle col^(((row>>1)&3)<<3).
// gload_lds path: linear LDS dest (wave-uniform base + lane*16), inverse-swizzled
// global source (same involution). Fallback: reg-staged swizzled writes.
#if HAS_GLLDS
#define STAGE_T(DST, SRC, ROWBASE, KK)                                                    \
  { _Pragma("unroll") for (int j_ = 0; j_ < 2; j_++) {                                    \
      int row_ = wave * 32 + j_ * 16 + (lane >> 2);                                       \
      int col_ = ((lane & 3) ^ ((row_ >> 1) & 3)) * 8;                                    \
      const u16* gp_ = (SRC) + (size_t)((ROWBASE) + row_) * 1024 + (KK) + col_;           \
      __builtin_amdgcn_global_load_lds(                                                   \
          (const __attribute__((address_space(1))) unsigned int*)gp_,                     \
          (__attribute__((address_space(3))) unsigned int*)((DST) + (wave * 2 + j_) * 512), \
          16, 0, 0); } }
#else
#define STAGE_T(DST, SRC, ROWBASE, KK)                                                    \
  { int row_ = tid >> 1, cb_ = (tid & 1) * 16;                                            \
    const u16* gp_ = (SRC) + (size_t)((ROWBASE) + row_) * 1024 + (KK) + cb_;              \
    int g_ = ((row_ >> 1) & 3) << 3;                                                      \
    *(u16x8*)&(DST)[row_ * 32 + (cb_ ^ g_)]       = *(const u16x8*)gp_;                   \
    *(u16x8*)&(DST)[row_ * 32 + ((cb_ + 8) ^ g_)] = *(const u16x8*)(gp_ + 8); }
#endif

// ---------------- converts ----------------
__global__ __launch_bounds__(256) void k_half(const float* __restrict__ s, u16* __restrict__ d) {
    size_t i = ((size_t)blockIdx.x * 256 + threadIdx.x) * 4;
    f32x4 v = *(const f32x4*)(s + i);
    u16x4 h;
#pragma unroll
    for (int j = 0; j < 4; j++) h[j] = f2h(v[j]);
    *(u16x4*)(d + i) = h;
}

// wt[m*64+d] = omega[d*256+m] * DH^-0.25 (fp16)
__global__ __launch_bounds__(256) void k_omega(const float* __restrict__ om, u16* __restrict__ wh) {
    int i = blockIdx.x * 256 + threadIdx.x; // 16384
    int m = i >> 6, d = i & 63;
    wh[i] = f2h(om[d * 256 + m] * 0.35355339059327373f);
}

__global__ __launch_bounds__(256) void k_zero(float* __restrict__ p, int n) {
    int i = (blockIdx.x * 256 + threadIdx.x) * 4;
    if (i < n) { f32x4 z; z[0]=0.f; z[1]=0.f; z[2]=0.f; z[3]=0.f; *(f32x4*)(p + i) = z; }
}

// ---------------- QKV GEMM: fp16, swizzled LDS, gload_lds, counted-vmcnt depth-2 pipeline ----------------
// Output: Q,K (n0<2048) -> QK[row][2048] fp16 ; V (n0>=2048) -> Vb fp16.
__global__ __launch_bounds__(256) void k_gemm_qkv(
    const u16* __restrict__ Ax, const u16* __restrict__ Bw,
    u16* __restrict__ QK, u16* __restrict__ Vb) {
    __shared__ __align__(16) u16 sm[16384]; // 32 KB: 2 bufs x 2 x [128][32] tiles; epilogue fits
    const int tid = threadIdx.x, wave = tid >> 6, lane = tid & 63;
    const int lr = lane & 15, lk = (lane >> 4) * 8;
    const int m0 = blockIdx.y * 128, n0 = blockIdx.x * 128;
    const int wm = (wave >> 1) * 64, wn = (wave & 1) * 64;
    const int sec = n0 >> 10;
    constexpr int TILE = 4096, BUF = 8192;

    int aoff[4], boff[4];
#pragma unroll
    for (int f = 0; f < 4; f++) {
        int ra = wm + f * 16 + lr;
        aoff[f] = ra * 32 + (lk ^ (((ra >> 1) & 3) << 3));
        int rb = wn + f * 16 + lr;
        boff[f] = rb * 32 + (lk ^ (((rb >> 1) & 3) << 3));
    }

    f32x4 acc[4][4];
#pragma unroll
    for (int i = 0; i < 4; i++)
#pragma unroll
        for (int j = 0; j < 4; j++)
#pragma unroll
            for (int r = 0; r < 4; r++) acc[i][j][r] = 0.f;

#if HAS_GLLDS
    // depth-2 prologue: steps 0 and 1 in flight (8 loads/wave)
    STAGE_T(sm,              Ax, m0, 0)
    STAGE_T(sm + TILE,       Bw, n0, 0)
    STAGE_T(sm + BUF,        Ax, m0, 32)
    STAGE_T(sm + BUF + TILE, Bw, n0, 32)
    int cur = 0;
    for (int t = 0; t < 32; ++t) {
        // wait for step-t tile (oldest 4 loads); keep step-(t+1)'s 4 in flight
        if (t < 31) { asm volatile("s_waitcnt vmcnt(4)" ::: "memory"); }
        else        { asm volatile("s_waitcnt vmcnt(0)" ::: "memory"); }
        __builtin_amdgcn_sched_barrier(0);
        __builtin_amdgcn_s_barrier();        // all waves: buf[cur] ready
        __builtin_amdgcn_sched_barrier(0);
        u16* buf = sm + cur * BUF;
        f16x8 a[4], bb[4];
#pragma unroll
        for (int f = 0; f < 4; f++) {
            a[f]  = *(const f16x8*)&buf[aoff[f]];
            bb[f] = *(const f16x8*)&buf[TILE + boff[f]];
        }
        asm volatile("s_waitcnt lgkmcnt(0)" ::: "memory");
        __builtin_amdgcn_sched_barrier(0);   // rule #18 fence
        __builtin_amdgcn_s_barrier();        // all waves done reading buf[cur]
        __builtin_amdgcn_sched_barrier(0);
        if (t < 30) {                        // stage step t+2 into freed buffer
            int kk = (t + 2) * 32;
            STAGE_T(buf,        Ax, m0, kk)
            STAGE_T(buf + TILE, Bw, n0, kk)
        }
#pragma unroll
        for (int i = 0; i < 4; i++)
#pragma unroll
            for (int j = 0; j < 4; j++)
                acc[i][j] = mfma16h(a[i], bb[j], acc[i][j]);
        cur ^= 1;
    }
#else
    STAGE_T(sm, Ax, m0, 0)
    STAGE_T(sm + TILE, Bw, n0, 0)
    __syncthreads();
    int cur = 0;
    for (int k0 = 0; k0 < 1024; k0 += 32) {
        u16* buf  = sm + cur * BUF;
        u16* nbuf = sm + (cur ^ 1) * BUF;
        if (k0 + 32 < 1024) {
            STAGE_T(nbuf, Ax, m0, k0 + 32)
            STAGE_T(nbuf + TILE, Bw, n0, k0 + 32)
        }
        f16x8 a[4], bb[4];
#pragma unroll
        for (int f = 0; f < 4; f++) {
            a[f]  = *(const f16x8*)&buf[aoff[f]];
            bb[f] = *(const f16x8*)&buf[TILE + boff[f]];
        }
#pragma unroll
        for (int i = 0; i < 4; i++)
#pragma unroll
            for (int j = 0; j < 4; j++)
                acc[i][j] = mfma16h(a[i], bb[j], acc[i][j]);
        __syncthreads();
        cur ^= 1;
    }
#endif

    // epilogue: restage 32-row groups through LDS for coalesced fp16 stores
    float* ep = (float*)sm; // [32][132] f32 = 16896 B
    for (int g = 0; g < 4; g++) {
        __syncthreads();
        if ((wave >> 1) == (g >> 1)) {
#pragma unroll
            for (int fi = 0; fi < 2; fi++) {
                int fm = (g & 1) * 2 + fi;
#pragma unroll
                for (int j = 0; j < 4; j++)
#pragma unroll
                    for (int r = 0; r < 4; r++)
                        ep[(fi * 16 + (lane >> 4) * 4 + r) * 132 + wn + j * 16 + lr] = acc[fm][j][r];
            }
        }
        __syncthreads();
        int row = tid >> 3, c0 = (tid & 7) * 16;
        int grow = m0 + g * 32 + row;
        u16x8 h0, h1;
#pragma unroll
        for (int j = 0; j < 8; j++) {
            h0[j] = f2h(ep[row * 132 + c0 + j]);
            h1[j] = f2h(ep[row * 132 + c0 + 8 + j]);
        }
        if (sec < 2) {
            size_t o = (size_t)grow * 2048 + (n0 + c0);
            *(u16x8*)(QK + o) = h0; *(u16x8*)(QK + o + 8) = h1;
        } else {
            size_t o = (size_t)grow * 1024 + (n0 - 2048 + c0);
            *(u16x8*)(Vb + o) = h0; *(u16x8*)(Vb + o + 8) = h1;
        }
    }
}

// ---------------- fused phi(K) + KV + Ksum (fp16; phi(K) scaled by extra 1/16) ----------------
__global__ __launch_bounds__(256) void k_phik_kv(
    const u16* __restrict__ QK, const u16* __restrict__ wt,
    const u16* __restrict__ Vb, float* __restrict__ KVacc, float* __restrict__ Ksum) {
    __shared__ __align__(16) u16 sKh[64 * 72];
    __shared__ __align__(16) u16 sVt[64 * 72];
    __shared__ __align__(16) u16 sKfT[256 * 72];
    __shared__ float snsq[64];
    const int tid = threadIdx.x, wave = tid >> 6, lane = tid & 63;
    const int lr = lane & 15, lk = (lane >> 4) * 8;
    const int kc = blockIdx.x, bh = blockIdx.y;
    const int b = bh >> 4, h = bh & 15;

    f16x8 wb[4][2];
#pragma unroll
    for (int fn = 0; fn < 4; fn++)
#pragma unroll
        for (int ks = 0; ks < 2; ks++)
            wb[fn][ks] = *(const f16x8*)(wt + (size_t)(wave * 64 + fn * 16 + lr) * 64 + ks * 32 + lk);

    f32x4 akv[4][4];
#pragma unroll
    for (int i = 0; i < 4; i++)
#pragma unroll
        for (int j = 0; j < 4; j++)
#pragma unroll
            for (int r = 0; r < 4; r++) akv[i][j][r] = 0.f;
    float ksm[4] = {0.f, 0.f, 0.f, 0.f};

    for (int it = 0; it < 4; it++) {
        int l0 = kc * 256 + it * 64;
        __syncthreads();
        { // stage K + nsq
            int row = tid >> 2, c0 = (tid & 3) * 16;
            size_t g = ((size_t)(b * Ll + l0 + row)) * 2048 + 1024 + h * 64 + c0;
            u16x8 h0 = *(const u16x8*)(QK + g);
            u16x8 h1 = *(const u16x8*)(QK + g + 8);
            *(u16x8*)&sKh[row * 72 + c0]     = h0;
            *(u16x8*)&sKh[row * 72 + c0 + 8] = h1;
            float s = 0.f;
#pragma unroll
            for (int j = 0; j < 8; j++) {
                float a = h2f(h0[j]); s += a * a;
                float c = h2f(h1[j]); s += c * c;
            }
            s += __shfl_xor(s, 1); s += __shfl_xor(s, 2);
            if ((tid & 3) == 0) snsq[row] = s * 0.0625f;
        }
        { // stage V transposed
            int l = tid >> 2, d0 = (tid & 3) * 16;
            size_t g = ((size_t)(b * Ll + l0 + l)) * 1024 + h * 64 + d0;
            u16x8 v0 = *(const u16x8*)(Vb + g);
            u16x8 v1 = *(const u16x8*)(Vb + g + 8);
#pragma unroll
            for (int j = 0; j < 8; j++) {
                sVt[(d0 + j) * 72 + l] = v0[j];
                sVt[(d0 + 8 + j) * 72 + l] = v1[j];
            }
        }
        __syncthreads();
#pragma unroll
        for (int fm = 0; fm < 4; fm++) {
            f32x4 ap[4];
#pragma unroll
            for (int fn = 0; fn < 4; fn++)
#pragma unroll
                for (int r = 0; r < 4; r++) ap[fn][r] = 0.f;
#pragma unroll
            for (int ks = 0; ks < 2; ks++) {
                f16x8 aH = *(const f16x8*)&sKh[(fm * 16 + lr) * 72 + ks * 32 + lk];
#pragma unroll
                for (int fn = 0; fn < 4; fn++)
                    ap[fn] = mfma16h(aH, wb[fn][ks], ap[fn]);
            }
#pragma unroll
            for (int fn = 0; fn < 4; fn++) {
                u16x4 pk;
#pragma unroll
                for (int r = 0; r < 4; r++) {
                    float ns = snsq[fm * 16 + (lane >> 4) * 4 + r];
                    float val = __expf(ap[fn][r] - ns) * 0.00390625f; // 1/256 (extra 1/16 folded)
                    ksm[fn] += val;
                    pk[r] = f2h(val);
                }
                *(u16x4*)&sKfT[(wave * 64 + fn * 16 + lr) * 72 + fm * 16 + (lane >> 4) * 4] = pk;
            }
        }
#pragma unroll
        for (int ks = 0; ks < 2; ks++) {
            f16x8 a4[4], b4[4];
#pragma unroll
            for (int f = 0; f < 4; f++) {
                a4[f] = *(const f16x8*)&sKfT[(wave * 64 + f * 16 + lr) * 72 + ks * 32 + lk];
                b4[f] = *(const f16x8*)&sVt[(f * 16 + lr) * 72 + ks * 32 + lk];
            }
#pragma unroll
            for (int fm = 0; fm < 4; fm++)
#pragma unroll
                for (int fn = 0; fn < 4; fn++)
                    akv[fm][fn] = mfma16h(a4[fm], b4[fn], akv[fm][fn]);
        }
    }
#pragma unroll
    for (int fm = 0; fm < 4; fm++)
#pragma unroll
        for (int fn = 0; fn < 4; fn++)
#pragma unroll
            for (int r = 0; r < 4; r++) {
                int m = wave * 64 + fm * 16 + (lane >> 4) * 4 + r;
                int d = fn * 16 + lr;
                atomicAdd(&KVacc[((size_t)bh << 14) + m * 64 + d], akv[fm][fn][r]);
            }
#pragma unroll
    for (int fn = 0; fn < 4; fn++) {
        ksm[fn] += __shfl_xor(ksm[fn], 16);
        ksm[fn] += __shfl_xor(ksm[fn], 32);
    }
    if (lane < 16) {
#pragma unroll
        for (int fn = 0; fn < 4; fn++)
            atomicAdd(&Ksum[bh * 256 + wave * 64 + fn * 16 + lane], ksm[fn]);
    }
}

// KVt[bh][d][m] = fp16(KVacc[bh][m][d])
__global__ __launch_bounds__(256) void k_kvt(const float* __restrict__ KVacc, u16* __restrict__ KVt) {
    int i = blockIdx.x * 256 + threadIdx.x;
    int bh = i >> 14, dd = (i >> 8) & 63, m = i & 255;
    KVt[i] = f2h(KVacc[((size_t)bh << 14) + m * 64 + dd]);
}

// ---------------- fused phi(Q) + norm + attn (fp16) ----------------
__global__ __launch_bounds__(512) void k_phiq_attn(
    const u16* __restrict__ QK, const u16* __restrict__ wt,
    const u16* __restrict__ KVt, const float* __restrict__ Ksum,
    u16* __restrict__ attn) {
    __shared__ __align__(16) u16 sQh[64 * 72];
    __shared__ __align__(16) u16 sQf[64 * 264];
    __shared__ float sKs[256];
    __shared__ float snsq[64];
    __shared__ float snorm[64];
    const int tid = threadIdx.x, wave = tid >> 6, lane = tid & 63;
    const int lr = lane & 15, lk = (lane >> 4) * 8;
    const int bh = blockIdx.y, b = bh >> 4, h = bh & 15;
    const int mq = wave & 3;
    const int lh = wave >> 2;
    const int af = wave & 3;
    const int ad = wave >> 2;

    f16x8 wb[4][2];
#pragma unroll
    for (int fn = 0; fn < 4; fn++)
#pragma unroll
        for (int ks = 0; ks < 2; ks++)
            wb[fn][ks] = *(const f16x8*)(wt + (size_t)(mq * 64 + fn * 16 + lr) * 64 + ks * 32 + lk);
    f16x8 kvb[2][8];
#pragma unroll
    for (int fn = 0; fn < 2; fn++)
#pragma unroll
        for (int ks = 0; ks < 8; ks++)
            kvb[fn][ks] = *(const f16x8*)(KVt + ((size_t)bh << 14) +
                                          (size_t)(ad * 32 + fn * 16 + lr) * 256 + ks * 32 + lk);
    if (tid < 256) sKs[tid] = Ksum[bh * 256 + tid];

    for (int st = 0; st < 2; st++) {
        const int l0 = (blockIdx.x * 2 + st) * 64;
        __syncthreads();
        {
            int row = tid >> 3, c0 = (tid & 7) * 8;
            size_t g = ((size_t)(b * Ll + l0 + row)) * 2048 + h * 64 + c0;
            u16x8 vh = *(const u16x8*)(QK + g);
            *(u16x8*)&sQh[row * 72 + c0] = vh;
            float s = 0.f;
#pragma unroll
            for (int j = 0; j < 8; j++) { float a = h2f(vh[j]); s += a * a; }
            s += __shfl_xor(s, 1); s += __shfl_xor(s, 2); s += __shfl_xor(s, 4);
            if ((tid & 7) == 0) snsq[row] = s * 0.0625f;
        }
        __syncthreads();
#pragma unroll
        for (int fm = 0; fm < 2; fm++) {
            f32x4 ap[4];
#pragma unroll
            for (int fn = 0; fn < 4; fn++)
#pragma unroll
                for (int r = 0; r < 4; r++) ap[fn][r] = 0.f;
#pragma unroll
            for (int ks = 0; ks < 2; ks++) {
                f16x8 aH = *(const f16x8*)&sQh[(lh * 32 + fm * 16 + lr) * 72 + ks * 32 + lk];
#pragma unroll
                for (int fn = 0; fn < 4; fn++)
                    ap[fn] = mfma16h(aH, wb[fn][ks], ap[fn]);
            }
#pragma unroll
            for (int fn = 0; fn < 4; fn++)
#pragma unroll
                for (int r = 0; r < 4; r++) {
                    int l = lh * 32 + fm * 16 + (lane >> 4) * 4 + r;
                    int m = mq * 64 + fn * 16 + lr;
                    sQf[l * 264 + m] = f2h(__expf(ap[fn][r] - snsq[l]) * 0.0625f);
                }
        }
        __syncthreads();
        { // norm[l] = sum_m Qf * Ksum, vectorized LDS reads
            int l = tid >> 3, m0 = (tid & 7) * 32;
            float s = 0.f;
#pragma unroll
            for (int j4 = 0; j4 < 4; j4++) {
                u16x8 qv = *(const u16x8*)&sQf[l * 264 + m0 + j4 * 8];
#pragma unroll
                for (int j = 0; j < 8; j++) s += h2f(qv[j]) * sKs[m0 + j4 * 8 + j];
            }
            s += __shfl_xor(s, 1); s += __shfl_xor(s, 2); s += __shfl_xor(s, 4);
            if ((tid & 7) == 0) snorm[l] = s;
        }
        f32x4 aa[2];
#pragma unroll
        for (int fn = 0; fn < 2; fn++)
#pragma unroll
            for (int r = 0; r < 4; r++) aa[fn][r] = 0.f;
#pragma unroll
        for (int ks = 0; ks < 8; ks++) {
            f16x8 a = *(const f16x8*)&sQf[(af * 16 + lr) * 264 + ks * 32 + lk];
            aa[0] = mfma16h(a, kvb[0][ks], aa[0]);
            aa[1] = mfma16h(a, kvb[1][ks], aa[1]);
        }
        __syncthreads();
        float* ep = (float*)sQf; // [64][68]
#pragma unroll
        for (int fn = 0; fn < 2; fn++)
#pragma unroll
            for (int r = 0; r < 4; r++) {
                int l = af * 16 + (lane >> 4) * 4 + r;
                int d = ad * 32 + fn * 16 + lr;
                ep[l * 68 + d] = aa[fn][r];
            }
        __syncthreads();
        {
            int l = tid >> 3, d0 = (tid & 7) * 8;
            // norm carries 1/16 from phi(K) extra scale: clamp = 1e-6/16
            float inv = 1.0f / fmaxf(snorm[l], 6.25e-8f);
            u16x8 o;
#pragma unroll
            for (int j = 0; j < 8; j++) o[j] = f2h(ep[l * 68 + d0 + j] * inv);
            *(u16x8*)(attn + ((size_t)(b * Ll + l0 + l)) * 1024 + h * 64 + d0) = o;
        }
    }
}

// ---------------- final GEMM: attn @ Wo^T + bo -> f32 out (fp16, pipelined) ----------------
__global__ __launch_bounds__(256) void k_gemm_out(const u16* __restrict__ Ab, const u16* __restrict__ Bw,
                                                  const float* __restrict__ bias, float* __restrict__ outp) {
    __shared__ __align__(16) u16 sm[16896];
    const int tid = threadIdx.x, wave = tid >> 6, lane = tid & 63;
    const int lr = lane & 15, lk = (lane >> 4) * 8;
    const int m0 = blockIdx.y * 128, n0 = blockIdx.x * 128;
    const int wm = (wave >> 1) * 64, wn = (wave & 1) * 64;
    constexpr int TILE = 4096, BUF = 8192;

    int aoff[4], boff[4];
#pragma unroll
    for (int f = 0; f < 4; f++) {
        int ra = wm + f * 16 + lr;
        aoff[f] = ra * 32 + (lk ^ (((ra >> 1) & 3) << 3));
        int rb = wn + f * 16 + lr;
        boff[f] = rb * 32 + (lk ^ (((rb >> 1) & 3) << 3));
    }

    f32x4 acc[4][4];
#pragma unroll
    for (int i = 0; i < 4; i++)
#pragma unroll
        for (int j = 0; j < 4; j++)
#pragma unroll
            for (int r = 0; r < 4; r++) acc[i][j][r] = 0.f;

#if HAS_GLLDS
    STAGE_T(sm,              Ab, m0, 0)
    STAGE_T(sm + TILE,       Bw, n0, 0)
    STAGE_T(sm + BUF,        Ab, m0, 32)
    STAGE_T(sm + BUF + TILE, Bw, n0, 32)
    int cur = 0;
    for (int t = 0; t < 32; ++t) {
        if (t < 31) { asm volatile("s_waitcnt vmcnt(4)" ::: "memory"); }
        else        { asm volatile("s_waitcnt vmcnt(0)" ::: "memory"); }
        __builtin_amdgcn_sched_barrier(0);
        __builtin_amdgcn_s_barrier();
        __builtin_amdgcn_sched_barrier(0);
        u16* buf = sm + cur * BUF;
        f16x8 a[4], bb[4];
#pragma unroll
        for (int f = 0; f < 4; f++) {
            a[f]  = *(const f16x8*)&buf[aoff[f]];
            bb[f] = *(const f16x8*)&buf[TILE + boff[f]];
        }
        asm volatile("s_waitcnt lgkmcnt(0)" ::: "memory");
        __builtin_amdgcn_sched_barrier(0);
        __builtin_amdgcn_s_barrier();
        __builtin_amdgcn_sched_barrier(0);
        if (t < 30) {
            int kk = (t + 2) * 32;
            STAGE_T(buf,        Ab, m0, kk)
            STAGE_T(buf + TILE, Bw, n0, kk)
        }
#pragma unroll
        for (int i = 0; i < 4; i++)
#pragma unroll
            for (int j = 0; j < 4; j++)
                acc[i][j] = mfma16h(a[i], bb[j], acc[i][j]);
        cur ^= 1;
    }
#else
    STAGE_T(sm, Ab, m0, 0)
    STAGE_T(sm + TILE, Bw, n0, 0)
    __syncthreads();
    int cur = 0;
    for (int k0 = 0; k0 < 1024; k0 += 32) {
        u16* buf  = sm + cur * BUF;
        u16* nbuf = sm + (cur ^ 1) * BUF;
        if (k0 + 32 < 1024) {
            STAGE_T(nbuf, Ab, m0, k0 + 32)
            STAGE_T(nbuf + TILE, Bw, n0, k0 + 32)
        }
        f16x8 a[4], bb[4];
#pragma unroll
        for (int f = 0; f < 4; f++) {
            a[f]  = *(const f16x8*)&buf[aoff[f]];
            bb[f] = *(const f16x8*)&buf[TILE + boff[f]];
        }
#pragma unroll
        for (int i = 0; i < 4; i++)
#pragma unroll
            for (int j = 0; j < 4; j++)
                acc[i][j] = mfma16h(a[i], bb[j], acc[i][j]);
        __syncthreads();
        cur ^= 1;
    }
#endif
    float* ep = (float*)sm; // [32][132]
    for (int g = 0; g < 4; g++) {
        __syncthreads();
        if ((wave >> 1) == (g >> 1)) {
#pragma unroll
            for (int fi = 0; fi < 2; fi++) {
                int fm = (g & 1) * 2 + fi;
#pragma unroll
                for (int j = 0; j < 4; j++)
#pragma unroll
                    for (int r = 0; r < 4; r++)
                        ep[(fi * 16 + (lane >> 4) * 4 + r) * 132 + wn + j * 16 + lr] = acc[fm][j][r];
            }
        }
        __syncthreads();
        int row = tid >> 3, c0 = (tid & 7) * 16;
        int grow = m0 + g * 32 + row;
        float vv[16];
#pragma unroll
        for (int j = 0; j < 16; j++) vv[j] = ep[row * 132 + c0 + j] + bias[n0 + c0 + j];
#pragma unroll
        for (int p = 0; p < 4; p++) {
            f32x4 t;
#pragma unroll
            for (int q = 0; q < 4; q++) t[q] = vv[p * 4 + q];
            *(f32x4*)(outp + (size_t)grow * 1024 + n0 + c0 + p * 4) = t;
        }
    }
}

extern "C" void kernel_launch(void* const* d_in, const int* in_sizes, int n_in,
                              void* d_out, int out_size, void* d_ws, size_t ws_size,
                              hipStream_t stream) {
    (void)in_sizes; (void)n_in; (void)out_size; (void)ws_size;
    const float* x  = (const float*)d_in[0];
    const float* Wq = (const float*)d_in[1];
    const float* Wk = (const float*)d_in[2];
    const float* Wv = (const float*)d_in[3];
    const float* Wo = (const float*)d_in[4];
    const float* bo = (const float*)d_in[5];
    const float* om = (const float*)d_in[6];

    char* w = (char*)d_ws;
    size_t o = 0;
    auto take = [&](size_t n) { char* p = w + o; o += n; return p; };
    u16* QK  = (u16*)take(67108864);   // [16384][2048] fp16: Q | K
    u16* Vb  = (u16*)take(33554432);   // [16384][1024] fp16
    u16* xh  = (u16*)take(33554432);   // x fp16
    u16* Wc  = (u16*)take(6291456);    // Wq|Wk|Wv fp16 [3072][1024]
    u16* Wof = (u16*)take(2097152);    // Wo fp16
    u16* wt  = (u16*)take(32768);      // omega^T scaled fp16 [256][64]
    float* KVacc = (float*)take(4194304);
    float* Ksum  = (float*)take(65536);  // contiguous after KVacc for k_zero
    u16* KVt = (u16*)take(2097152);
    u16* attn = Vb; // alias: V dead after k_phik_kv

    k_half<<<16384, 256, 0, stream>>>(x, xh);
    k_half<<<1024, 256, 0, stream>>>(Wq, Wc);
    k_half<<<1024, 256, 0, stream>>>(Wk, Wc + 1048576);
    k_half<<<1024, 256, 0, stream>>>(Wv, Wc + 2097152);
    k_half<<<1024, 256, 0, stream>>>(Wo, Wof);
    k_omega<<<64, 256, 0, stream>>>(om, wt);
    k_zero<<<1040, 256, 0, stream>>>(KVacc, 1064960); // KVacc + Ksum

    k_gemm_qkv<<<dim3(24, 128), 256, 0, stream>>>(xh, Wc, QK, Vb);
    k_phik_kv<<<dim3(16, 64), 256, 0, stream>>>(QK, wt, Vb, KVacc, Ksum);
    k_kvt<<<4096, 256, 0, stream>>>(KVacc, KVt);
    k_phiq_attn<<<dim3(32, 64), 512, 0, stream>>>(QK, wt, KVt, Ksum, attn);
    k_gemm_out<<<dim3(8, 128), 256, 0, stream>>>(attn, Wof, bo, (float*)d_out);
}

// Round 7
// 412.262 us; speedup vs baseline: 1.0017x; 1.0017x over previous
//
#include <hip/hip_runtime.h>

typedef unsigned short u16;
typedef __attribute__((ext_vector_type(4))) float f32x4;
typedef _Float16 f16x8 __attribute__((ext_vector_type(8)));
typedef __attribute__((ext_vector_type(4))) u16   u16x4;
typedef __attribute__((ext_vector_type(8))) u16   u16x8;

#define DEV static __device__ __forceinline__

constexpr int Ll = 4096;

DEV float h2f(u16 v) { _Float16 h; __builtin_memcpy(&h, &v, 2); return (float)h; }
DEV u16 f2h(float f) { _Float16 h = (_Float16)f; u16 u; __builtin_memcpy(&u, &h, 2); return u; }

DEV f32x4 mfma16h(f16x8 a, f16x8 b, f32x4 c) {
    return __builtin_amdgcn_mfma_f32_16x16x32_f16(a, b, c, 0, 0, 0);
}

#if defined(__has_builtin)
#if __has_builtin(__builtin_amdgcn_global_load_lds)
#define HAS_GLLDS 1
#endif
#endif
#ifndef HAS_GLLDS
#define HAS_GLLDS 0
#endif

// ---- 256^2 GEMM staging: one 8KB unit (512 thr x 16B) of a [256][32] u16 tile ----
// LDS linear [row][chunk0..3] (chunk=8 halfs); LDS(row,c) holds global chunk c^((row>>1)&3).
// gload_lds: wave-uniform dest + lane*16; global source pre-swizzled (involution).
#if HAS_GLLDS
#define STG(BUF, U, SRC, ROWBASE, KK)                                                \
  { int rl_ = wave * 16 + (lane >> 2);                                               \
    int c_ = lane & 3;                                                               \
    int grow_ = (((U) & 1) * 128) + rl_;                                             \
    const u16* gp_ = (SRC) + (size_t)((ROWBASE) + grow_) * 1024 + (KK)               \
                     + ((c_ ^ ((rl_ >> 1) & 3)) * 8);                                \
    __builtin_amdgcn_global_load_lds(                                                \
        (const __attribute__((address_space(1))) unsigned int*)gp_,                  \
        (__attribute__((address_space(3))) unsigned int*)(sm + (BUF) * 16384 +       \
            (U) * 4096 + wave * 512), 16, 0, 0); }
#else
#define STG(BUF, U, SRC, ROWBASE, KK)                                                \
  { int rl_ = wave * 16 + (lane >> 2);                                               \
    int c_ = lane & 3;                                                               \
    int grow_ = (((U) & 1) * 128) + rl_;                                             \
    const u16* gp_ = (SRC) + (size_t)((ROWBASE) + grow_) * 1024 + (KK)               \
                     + ((c_ ^ ((rl_ >> 1) & 3)) * 8);                                \
    *(u16x8*)(sm + (BUF) * 16384 + (U) * 4096 + wave * 512 + lane * 8)               \
        = *(const u16x8*)gp_; }
#endif

// ---------------- converts ----------------
__global__ __launch_bounds__(256) void k_half(const float* __restrict__ s, u16* __restrict__ d) {
    size_t i = ((size_t)blockIdx.x * 256 + threadIdx.x) * 4;
    f32x4 v = *(const f32x4*)(s + i);
    u16x4 h;
#pragma unroll
    for (int j = 0; j < 4; j++) h[j] = f2h(v[j]);
    *(u16x4*)(d + i) = h;
}

// wt[m*64+d] = omega[d*256+m] * DH^-0.25 (fp16)
__global__ __launch_bounds__(256) void k_omega(const float* __restrict__ om, u16* __restrict__ wh) {
    int i = blockIdx.x * 256 + threadIdx.x; // 16384
    int m = i >> 6, d = i & 63;
    wh[i] = f2h(om[d * 256 + m] * 0.35355339059327373f);
}

__global__ __launch_bounds__(256) void k_zero(float* __restrict__ p, int n) {
    int i = (blockIdx.x * 256 + threadIdx.x) * 4;
    if (i < n) { f32x4 z; z[0]=0.f; z[1]=0.f; z[2]=0.f; z[3]=0.f; *(f32x4*)(p + i) = z; }
}

// ---------------- QKV GEMM: 256x256 tile, BK=32, phase-barriered, 8 waves ----------------
// Output: Q,K (n0<2048) -> QK[row][2048] fp16 ; V (n0>=2048) -> Vb fp16.
__global__ __launch_bounds__(512, 2) void k_gemm_qkv(
    const u16* __restrict__ Ax, const u16* __restrict__ Bw,
    u16* __restrict__ QK, u16* __restrict__ Vb) {
    __shared__ __align__(16) u16 sm[32768]; // 64KB: 2 bufs x (A[256][32] | B[256][32])
    const int tid = threadIdx.x, wave = tid >> 6, lane = tid & 63;
    const int lr = lane & 15, lkq = lane >> 4;
    const int wr = wave >> 2, wc = wave & 3;
    const int m0 = blockIdx.y * 256, n0 = blockIdx.x * 256;
    const int sec = n0 >> 10;

    int aoff[8], boff[4];
#pragma unroll
    for (int f = 0; f < 8; f++) {
        int row = wr * 128 + f * 16 + lr;
        aoff[f] = row * 32 + ((lkq ^ ((row >> 1) & 3)) * 8);
    }
#pragma unroll
    for (int f = 0; f < 4; f++) {
        int row = wc * 64 + f * 16 + lr;
        boff[f] = row * 32 + ((lkq ^ ((row >> 1) & 3)) * 8);
    }

    f32x4 acc[8][4];
#pragma unroll
    for (int i = 0; i < 8; i++)
#pragma unroll
        for (int j = 0; j < 4; j++)
#pragma unroll
            for (int r = 0; r < 4; r++) acc[i][j][r] = 0.f;

    // prologue: stage tile 0 into buf 0
    STG(0, 0, Ax, m0, 0) STG(0, 1, Ax, m0, 0)
    STG(0, 2, Bw, n0, 0) STG(0, 3, Bw, n0, 0)
    asm volatile("s_waitcnt vmcnt(0)" ::: "memory");
    __builtin_amdgcn_sched_barrier(0);
    __builtin_amdgcn_s_barrier();
    __builtin_amdgcn_sched_barrier(0);

    int cb = 0;
    for (int t = 0; t < 32; ++t) {
        const u16* Abase = sm + cb * 16384;
        const u16* Bbase = Abase + 8192;
        f16x8 afr[4], bfr[4];
        // ---- phase 0: B + A(lo) reads, stage next tile, 16 MFMA ----
#pragma unroll
        for (int f = 0; f < 4; f++) bfr[f] = *(const f16x8*)&Bbase[boff[f]];
#pragma unroll
        for (int f = 0; f < 4; f++) afr[f] = *(const f16x8*)&Abase[aoff[f]];
        if (t < 31) {
            int kk = (t + 1) * 32;
            STG(cb ^ 1, 0, Ax, m0, kk) STG(cb ^ 1, 1, Ax, m0, kk)
            STG(cb ^ 1, 2, Bw, n0, kk) STG(cb ^ 1, 3, Bw, n0, kk)
        }
        __builtin_amdgcn_sched_barrier(0);
        __builtin_amdgcn_s_barrier();
        asm volatile("s_waitcnt lgkmcnt(0)" ::: "memory");
        __builtin_amdgcn_sched_barrier(0);
        __builtin_amdgcn_s_setprio(1);
#pragma unroll
        for (int i = 0; i < 4; i++)
#pragma unroll
            for (int j = 0; j < 4; j++)
                acc[i][j] = mfma16h(afr[i], bfr[j], acc[i][j]);
        __builtin_amdgcn_s_setprio(0);
        __builtin_amdgcn_sched_barrier(0);
        __builtin_amdgcn_s_barrier();
        __builtin_amdgcn_sched_barrier(0);
        // ---- phase 1: A(hi) reads, 16 MFMA, drain stages ----
#pragma unroll
        for (int f = 0; f < 4; f++) afr[f] = *(const f16x8*)&Abase[aoff[4 + f]];
        __builtin_amdgcn_sched_barrier(0);
        __builtin_amdgcn_s_barrier();
        asm volatile("s_waitcnt lgkmcnt(0)" ::: "memory");
        __builtin_amdgcn_sched_barrier(0);
        __builtin_amdgcn_s_setprio(1);
#pragma unroll
        for (int i = 0; i < 4; i++)
#pragma unroll
            for (int j = 0; j < 4; j++)
                acc[4 + i][j] = mfma16h(afr[i], bfr[j], acc[4 + i][j]);
        __builtin_amdgcn_s_setprio(0);
        asm volatile("s_waitcnt vmcnt(0)" ::: "memory"); // next tile landed (covered by 32 MFMA)
        __builtin_amdgcn_sched_barrier(0);
        __builtin_amdgcn_s_barrier();
        __builtin_amdgcn_sched_barrier(0);
        cb ^= 1;
    }

    // epilogue: 8 groups of 32 rows restaged through LDS, coalesced fp16 stores
    float* ep = (float*)sm; // [32][264] f32 = 33792 B
    for (int g = 0; g < 8; g++) {
        __syncthreads();
        if (wr == (g >> 2)) {
#pragma unroll
            for (int fi = 0; fi < 2; fi++) {
                int fm = (g & 3) * 2 + fi;
#pragma unroll
                for (int fn = 0; fn < 4; fn++)
#pragma unroll
                    for (int r = 0; r < 4; r++)
                        ep[(fi * 16 + (lane >> 4) * 4 + r) * 264 + wc * 64 + fn * 16 + lr] = acc[fm][fn][r];
            }
        }
        __syncthreads();
        int row = tid >> 4, c0 = (tid & 15) * 16;
        int grow = m0 + g * 32 + row;
        u16x8 h0, h1;
#pragma unroll
        for (int j = 0; j < 8; j++) {
            h0[j] = f2h(ep[row * 264 + c0 + j]);
            h1[j] = f2h(ep[row * 264 + c0 + 8 + j]);
        }
        if (sec < 2) {
            size_t o = (size_t)grow * 2048 + (n0 + c0);
            *(u16x8*)(QK + o) = h0; *(u16x8*)(QK + o + 8) = h1;
        } else {
            size_t o = (size_t)grow * 1024 + (n0 - 2048 + c0);
            *(u16x8*)(Vb + o) = h0; *(u16x8*)(Vb + o + 8) = h1;
        }
    }
}

// ---------------- final GEMM: attn @ Wo^T + bo -> f32 out (same 256^2 structure) ----------------
__global__ __launch_bounds__(512, 2) void k_gemm_out(
    const u16* __restrict__ Ab, const u16* __restrict__ Bw,
    const float* __restrict__ bias, float* __restrict__ outp) {
    __shared__ __align__(16) u16 sm[32768];
    const int tid = threadIdx.x, wave = tid >> 6, lane = tid & 63;
    const int lr = lane & 15, lkq = lane >> 4;
    const int wr = wave >> 2, wc = wave & 3;
    const int m0 = blockIdx.y * 256, n0 = blockIdx.x * 256;

    int aoff[8], boff[4];
#pragma unroll
    for (int f = 0; f < 8; f++) {
        int row = wr * 128 + f * 16 + lr;
        aoff[f] = row * 32 + ((lkq ^ ((row >> 1) & 3)) * 8);
    }
#pragma unroll
    for (int f = 0; f < 4; f++) {
        int row = wc * 64 + f * 16 + lr;
        boff[f] = row * 32 + ((lkq ^ ((row >> 1) & 3)) * 8);
    }

    f32x4 acc[8][4];
#pragma unroll
    for (int i = 0; i < 8; i++)
#pragma unroll
        for (int j = 0; j < 4; j++)
#pragma unroll
            for (int r = 0; r < 4; r++) acc[i][j][r] = 0.f;

    STG(0, 0, Ab, m0, 0) STG(0, 1, Ab, m0, 0)
    STG(0, 2, Bw, n0, 0) STG(0, 3, Bw, n0, 0)
    asm volatile("s_waitcnt vmcnt(0)" ::: "memory");
    __builtin_amdgcn_sched_barrier(0);
    __builtin_amdgcn_s_barrier();
    __builtin_amdgcn_sched_barrier(0);

    int cb = 0;
    for (int t = 0; t < 32; ++t) {
        const u16* Abase = sm + cb * 16384;
        const u16* Bbase = Abase + 8192;
        f16x8 afr[4], bfr[4];
#pragma unroll
        for (int f = 0; f < 4; f++) bfr[f] = *(const f16x8*)&Bbase[boff[f]];
#pragma unroll
        for (int f = 0; f < 4; f++) afr[f] = *(const f16x8*)&Abase[aoff[f]];
        if (t < 31) {
            int kk = (t + 1) * 32;
            STG(cb ^ 1, 0, Ab, m0, kk) STG(cb ^ 1, 1, Ab, m0, kk)
            STG(cb ^ 1, 2, Bw, n0, kk) STG(cb ^ 1, 3, Bw, n0, kk)
        }
        __builtin_amdgcn_sched_barrier(0);
        __builtin_amdgcn_s_barrier();
        asm volatile("s_waitcnt lgkmcnt(0)" ::: "memory");
        __builtin_amdgcn_sched_barrier(0);
        __builtin_amdgcn_s_setprio(1);
#pragma unroll
        for (int i = 0; i < 4; i++)
#pragma unroll
            for (int j = 0; j < 4; j++)
                acc[i][j] = mfma16h(afr[i], bfr[j], acc[i][j]);
        __builtin_amdgcn_s_setprio(0);
        __builtin_amdgcn_sched_barrier(0);
        __builtin_amdgcn_s_barrier();
        __builtin_amdgcn_sched_barrier(0);
#pragma unroll
        for (int f = 0; f < 4; f++) afr[f] = *(const f16x8*)&Abase[aoff[4 + f]];
        __builtin_amdgcn_sched_barrier(0);
        __builtin_amdgcn_s_barrier();
        asm volatile("s_waitcnt lgkmcnt(0)" ::: "memory");
        __builtin_amdgcn_sched_barrier(0);
        __builtin_amdgcn_s_setprio(1);
#pragma unroll
        for (int i = 0; i < 4; i++)
#pragma unroll
            for (int j = 0; j < 4; j++)
                acc[4 + i][j] = mfma16h(afr[i], bfr[j], acc[4 + i][j]);
        __builtin_amdgcn_s_setprio(0);
        asm volatile("s_waitcnt vmcnt(0)" ::: "memory");
        __builtin_amdgcn_sched_barrier(0);
        __builtin_amdgcn_s_barrier();
        __builtin_amdgcn_sched_barrier(0);
        cb ^= 1;
    }

    float* ep = (float*)sm; // [32][264]
    for (int g = 0; g < 8; g++) {
        __syncthreads();
        if (wr == (g >> 2)) {
#pragma unroll
            for (int fi = 0; fi < 2; fi++) {
                int fm = (g & 3) * 2 + fi;
#pragma unroll
                for (int fn = 0; fn < 4; fn++)
#pragma unroll
                    for (int r = 0; r < 4; r++)
                        ep[(fi * 16 + (lane >> 4) * 4 + r) * 264 + wc * 64 + fn * 16 + lr] = acc[fm][fn][r];
            }
        }
        __syncthreads();
        int row = tid >> 4, c0 = (tid & 15) * 16;
        int grow = m0 + g * 32 + row;
        float vv[16];
#pragma unroll
        for (int j = 0; j < 16; j++) vv[j] = ep[row * 264 + c0 + j] + bias[n0 + c0 + j];
#pragma unroll
        for (int p = 0; p < 4; p++) {
            f32x4 tv;
#pragma unroll
            for (int q = 0; q < 4; q++) tv[q] = vv[p * 4 + q];
            *(f32x4*)(outp + (size_t)grow * 1024 + n0 + c0 + p * 4) = tv;
        }
    }
}

// ---------------- fused phi(K) + KV + Ksum (fp16; phi(K) scaled by extra 1/16) ----------------
__global__ __launch_bounds__(256) void k_phik_kv(
    const u16* __restrict__ QK, const u16* __restrict__ wt,
    const u16* __restrict__ Vb, float* __restrict__ KVacc, float* __restrict__ Ksum) {
    __shared__ __align__(16) u16 sKh[64 * 72];
    __shared__ __align__(16) u16 sVt[64 * 72];
    __shared__ __align__(16) u16 sKfT[256 * 72];
    __shared__ float snsq[64];
    const int tid = threadIdx.x, wave = tid >> 6, lane = tid & 63;
    const int lr = lane & 15, lk = (lane >> 4) * 8;
    const int kc = blockIdx.x, bh = blockIdx.y;
    const int b = bh >> 4, h = bh & 15;

    f16x8 wb[4][2];
#pragma unroll
    for (int fn = 0; fn < 4; fn++)
#pragma unroll
        for (int ks = 0; ks < 2; ks++)
            wb[fn][ks] = *(const f16x8*)(wt + (size_t)(wave * 64 + fn * 16 + lr) * 64 + ks * 32 + lk);

    f32x4 akv[4][4];
#pragma unroll
    for (int i = 0; i < 4; i++)
#pragma unroll
        for (int j = 0; j < 4; j++)
#pragma unroll
            for (int r = 0; r < 4; r++) akv[i][j][r] = 0.f;
    float ksm[4] = {0.f, 0.f, 0.f, 0.f};

    for (int it = 0; it < 4; it++) {
        int l0 = kc * 256 + it * 64;
        __syncthreads();
        { // stage K + nsq
            int row = tid >> 2, c0 = (tid & 3) * 16;
            size_t g = ((size_t)(b * Ll + l0 + row)) * 2048 + 1024 + h * 64 + c0;
            u16x8 h0 = *(const u16x8*)(QK + g);
            u16x8 h1 = *(const u16x8*)(QK + g + 8);
            *(u16x8*)&sKh[row * 72 + c0]     = h0;
            *(u16x8*)&sKh[row * 72 + c0 + 8] = h1;
            float s = 0.f;
#pragma unroll
            for (int j = 0; j < 8; j++) {
                float a = h2f(h0[j]); s += a * a;
                float c = h2f(h1[j]); s += c * c;
            }
            s += __shfl_xor(s, 1); s += __shfl_xor(s, 2);
            if ((tid & 3) == 0) snsq[row] = s * 0.0625f;
        }
        { // stage V transposed
            int l = tid >> 2, d0 = (tid & 3) * 16;
            size_t g = ((size_t)(b * Ll + l0 + l)) * 1024 + h * 64 + d0;
            u16x8 v0 = *(const u16x8*)(Vb + g);
            u16x8 v1 = *(const u16x8*)(Vb + g + 8);
#pragma unroll
            for (int j = 0; j < 8; j++) {
                sVt[(d0 + j) * 72 + l] = v0[j];
                sVt[(d0 + 8 + j) * 72 + l] = v1[j];
            }
        }
        __syncthreads();
#pragma unroll
        for (int fm = 0; fm < 4; fm++) {
            f32x4 ap[4];
#pragma unroll
            for (int fn = 0; fn < 4; fn++)
#pragma unroll
                for (int r = 0; r < 4; r++) ap[fn][r] = 0.f;
#pragma unroll
            for (int ks = 0; ks < 2; ks++) {
                f16x8 aH = *(const f16x8*)&sKh[(fm * 16 + lr) * 72 + ks * 32 + lk];
#pragma unroll
                for (int fn = 0; fn < 4; fn++)
                    ap[fn] = mfma16h(aH, wb[fn][ks], ap[fn]);
            }
#pragma unroll
            for (int fn = 0; fn < 4; fn++) {
                u16x4 pk;
#pragma unroll
                for (int r = 0; r < 4; r++) {
                    float ns = snsq[fm * 16 + (lane >> 4) * 4 + r];
                    float val = __expf(ap[fn][r] - ns) * 0.00390625f; // 1/256 (extra 1/16 folded)
                    ksm[fn] += val;
                    pk[r] = f2h(val);
                }
                *(u16x4*)&sKfT[(wave * 64 + fn * 16 + lr) * 72 + fm * 16 + (lane >> 4) * 4] = pk;
            }
        }
#pragma unroll
        for (int ks = 0; ks < 2; ks++) {
            f16x8 a4[4], b4[4];
#pragma unroll
            for (int f = 0; f < 4; f++) {
                a4[f] = *(const f16x8*)&sKfT[(wave * 64 + f * 16 + lr) * 72 + ks * 32 + lk];
                b4[f] = *(const f16x8*)&sVt[(f * 16 + lr) * 72 + ks * 32 + lk];
            }
#pragma unroll
            for (int fm = 0; fm < 4; fm++)
#pragma unroll
                for (int fn = 0; fn < 4; fn++)
                    akv[fm][fn] = mfma16h(a4[fm], b4[fn], akv[fm][fn]);
        }
    }
#pragma unroll
    for (int fm = 0; fm < 4; fm++)
#pragma unroll
        for (int fn = 0; fn < 4; fn++)
#pragma unroll
            for (int r = 0; r < 4; r++) {
                int m = wave * 64 + fm * 16 + (lane >> 4) * 4 + r;
                int d = fn * 16 + lr;
                atomicAdd(&KVacc[((size_t)bh << 14) + m * 64 + d], akv[fm][fn][r]);
            }
#pragma unroll
    for (int fn = 0; fn < 4; fn++) {
        ksm[fn] += __shfl_xor(ksm[fn], 16);
        ksm[fn] += __shfl_xor(ksm[fn], 32);
    }
    if (lane < 16) {
#pragma unroll
        for (int fn = 0; fn < 4; fn++)
            atomicAdd(&Ksum[bh * 256 + wave * 64 + fn * 16 + lane], ksm[fn]);
    }
}

// KVt[bh][d][m] = fp16(KVacc[bh][m][d])
__global__ __launch_bounds__(256) void k_kvt(const float* __restrict__ KVacc, u16* __restrict__ KVt) {
    int i = blockIdx.x * 256 + threadIdx.x;
    int bh = i >> 14, dd = (i >> 8) & 63, m = i & 255;
    KVt[i] = f2h(KVacc[((size_t)bh << 14) + m * 64 + dd]);
}

// ---------------- fused phi(Q) + norm + attn (fp16) ----------------
__global__ __launch_bounds__(512) void k_phiq_attn(
    const u16* __restrict__ QK, const u16* __restrict__ wt,
    const u16* __restrict__ KVt, const float* __restrict__ Ksum,
    u16* __restrict__ attn) {
    __shared__ __align__(16) u16 sQh[64 * 72];
    __shared__ __align__(16) u16 sQf[64 * 264];
    __shared__ float sKs[256];
    __shared__ float snsq[64];
    __shared__ float snorm[64];
    const int tid = threadIdx.x, wave = tid >> 6, lane = tid & 63;
    const int lr = lane & 15, lk = (lane >> 4) * 8;
    const int bh = blockIdx.y, b = bh >> 4, h = bh & 15;
    const int mq = wave & 3;
    const int lh = wave >> 2;
    const int af = wave & 3;
    const int ad = wave >> 2;

    f16x8 wb[4][2];
#pragma unroll
    for (int fn = 0; fn < 4; fn++)
#pragma unroll
        for (int ks = 0; ks < 2; ks++)
            wb[fn][ks] = *(const f16x8*)(wt + (size_t)(mq * 64 + fn * 16 + lr) * 64 + ks * 32 + lk);
    f16x8 kvb[2][8];
#pragma unroll
    for (int fn = 0; fn < 2; fn++)
#pragma unroll
        for (int ks = 0; ks < 8; ks++)
            kvb[fn][ks] = *(const f16x8*)(KVt + ((size_t)bh << 14) +
                                          (size_t)(ad * 32 + fn * 16 + lr) * 256 + ks * 32 + lk);
    if (tid < 256) sKs[tid] = Ksum[bh * 256 + tid];

    for (int st = 0; st < 2; st++) {
        const int l0 = (blockIdx.x * 2 + st) * 64;
        __syncthreads();
        {
            int row = tid >> 3, c0 = (tid & 7) * 8;
            size_t g = ((size_t)(b * Ll + l0 + row)) * 2048 + h * 64 + c0;
            u16x8 vh = *(const u16x8*)(QK + g);
            *(u16x8*)&sQh[row * 72 + c0] = vh;
            float s = 0.f;
#pragma unroll
            for (int j = 0; j < 8; j++) { float a = h2f(vh[j]); s += a * a; }
            s += __shfl_xor(s, 1); s += __shfl_xor(s, 2); s += __shfl_xor(s, 4);
            if ((tid & 7) == 0) snsq[row] = s * 0.0625f;
        }
        __syncthreads();
#pragma unroll
        for (int fm = 0; fm < 2; fm++) {
            f32x4 ap[4];
#pragma unroll
            for (int fn = 0; fn < 4; fn++)
#pragma unroll
                for (int r = 0; r < 4; r++) ap[fn][r] = 0.f;
#pragma unroll
            for (int ks = 0; ks < 2; ks++) {
                f16x8 aH = *(const f16x8*)&sQh[(lh * 32 + fm * 16 + lr) * 72 + ks * 32 + lk];
#pragma unroll
                for (int fn = 0; fn < 4; fn++)
                    ap[fn] = mfma16h(aH, wb[fn][ks], ap[fn]);
            }
#pragma unroll
            for (int fn = 0; fn < 4; fn++)
#pragma unroll
                for (int r = 0; r < 4; r++) {
                    int l = lh * 32 + fm * 16 + (lane >> 4) * 4 + r;
                    int m = mq * 64 + fn * 16 + lr;
                    sQf[l * 264 + m] = f2h(__expf(ap[fn][r] - snsq[l]) * 0.0625f);
                }
        }
        __syncthreads();
        { // norm[l] = sum_m Qf * Ksum, vectorized LDS reads
            int l = tid >> 3, m0 = (tid & 7) * 32;
            float s = 0.f;
#pragma unroll
            for (int j4 = 0; j4 < 4; j4++) {
                u16x8 qv = *(const u16x8*)&sQf[l * 264 + m0 + j4 * 8];
#pragma unroll
                for (int j = 0; j < 8; j++) s += h2f(qv[j]) * sKs[m0 + j4 * 8 + j];
            }
            s += __shfl_xor(s, 1); s += __shfl_xor(s, 2); s += __shfl_xor(s, 4);
            if ((tid & 7) == 0) snorm[l] = s;
        }
        f32x4 aa[2];
#pragma unroll
        for (int fn = 0; fn < 2; fn++)
#pragma unroll
            for (int r = 0; r < 4; r++) aa[fn][r] = 0.f;
#pragma unroll
        for (int ks = 0; ks < 8; ks++) {
            f16x8 a = *(const f16x8*)&sQf[(af * 16 + lr) * 264 + ks * 32 + lk];
            aa[0] = mfma16h(a, kvb[0][ks], aa[0]);
            aa[1] = mfma16h(a, kvb[1][ks], aa[1]);
        }
        __syncthreads();
        float* ep = (float*)sQf; // [64][68]
#pragma unroll
        for (int fn = 0; fn < 2; fn++)
#pragma unroll
            for (int r = 0; r < 4; r++) {
                int l = af * 16 + (lane >> 4) * 4 + r;
                int d = ad * 32 + fn * 16 + lr;
                ep[l * 68 + d] = aa[fn][r];
            }
        __syncthreads();
        {
            int l = tid >> 3, d0 = (tid & 7) * 8;
            // norm carries 1/16 from phi(K) extra scale: clamp = 1e-6/16
            float inv = 1.0f / fmaxf(snorm[l], 6.25e-8f);
            u16x8 o;
#pragma unroll
            for (int j = 0; j < 8; j++) o[j] = f2h(ep[l * 68 + d0 + j] * inv);
            *(u16x8*)(attn + ((size_t)(b * Ll + l0 + l)) * 1024 + h * 64 + d0) = o;
        }
    }
}

extern "C" void kernel_launch(void* const* d_in, const int* in_sizes, int n_in,
                              void* d_out, int out_size, void* d_ws, size_t ws_size,
                              hipStream_t stream) {
    (void)in_sizes; (void)n_in; (void)out_size; (void)ws_size;
    const float* x  = (const float*)d_in[0];
    const float* Wq = (const float*)d_in[1];
    const float* Wk = (const float*)d_in[2];
    const float* Wv = (const float*)d_in[3];
    const float* Wo = (const float*)d_in[4];
    const float* bo = (const float*)d_in[5];
    const float* om = (const float*)d_in[6];

    char* w = (char*)d_ws;
    size_t o = 0;
    auto take = [&](size_t n) { char* p = w + o; o += n; return p; };
    u16* QK  = (u16*)take(67108864);   // [16384][2048] fp16: Q | K
    u16* Vb  = (u16*)take(33554432);   // [16384][1024] fp16
    u16* xh  = (u16*)take(33554432);   // x fp16
    u16* Wc  = (u16*)take(6291456);    // Wq|Wk|Wv fp16 [3072][1024]
    u16* Wof = (u16*)take(2097152);    // Wo fp16
    u16* wt  = (u16*)take(32768);      // omega^T scaled fp16 [256][64]
    float* KVacc = (float*)take(4194304);
    float* Ksum  = (float*)take(65536);  // contiguous after KVacc for k_zero
    u16* KVt = (u16*)take(2097152);
    u16* attn = Vb; // alias: V dead after k_phik_kv

    k_half<<<16384, 256, 0, stream>>>(x, xh);
    k_half<<<1024, 256, 0, stream>>>(Wq, Wc);
    k_half<<<1024, 256, 0, stream>>>(Wk, Wc + 1048576);
    k_half<<<1024, 256, 0, stream>>>(Wv, Wc + 2097152);
    k_half<<<1024, 256, 0, stream>>>(Wo, Wof);
    k_omega<<<64, 256, 0, stream>>>(om, wt);
    k_zero<<<1040, 256, 0, stream>>>(KVacc, 1064960); // KVacc + Ksum

    k_gemm_qkv<<<dim3(12, 64), 512, 0, stream>>>(xh, Wc, QK, Vb);
    k_phik_kv<<<dim3(16, 64), 256, 0, stream>>>(QK, wt, Vb, KVacc, Ksum);
    k_kvt<<<4096, 256, 0, stream>>>(KVacc, KVt);
    k_phiq_attn<<<dim3(32, 64), 512, 0, stream>>>(QK, wt, KVt, Ksum, attn);
    k_gemm_out<<<dim3(4, 64), 512, 0, stream>>>(attn, Wof, bo, (float*)d_out);
}

// Round 8
// 406.431 us; speedup vs baseline: 1.0161x; 1.0143x over previous
//
#include <hip/hip_runtime.h>

typedef unsigned short u16;
typedef __attribute__((ext_vector_type(4))) float f32x4;
typedef _Float16 f16x8 __attribute__((ext_vector_type(8)));
typedef __attribute__((ext_vector_type(4))) u16   u16x4;
typedef __attribute__((ext_vector_type(8))) u16   u16x8;

#define DEV static __device__ __forceinline__

constexpr int Ll = 4096;

DEV float h2f(u16 v) { _Float16 h; __builtin_memcpy(&h, &v, 2); return (float)h; }
DEV u16 f2h(float f) { _Float16 h = (_Float16)f; u16 u; __builtin_memcpy(&u, &h, 2); return u; }

DEV f32x4 mfma16h(f16x8 a, f16x8 b, f32x4 c) {
    return __builtin_amdgcn_mfma_f32_16x16x32_f16(a, b, c, 0, 0, 0);
}

#if defined(__has_builtin)
#if __has_builtin(__builtin_amdgcn_global_load_lds)
#define HAS_GLLDS 1
#endif
#endif
#ifndef HAS_GLLDS
#define HAS_GLLDS 0
#endif

#define SBAR()  __builtin_amdgcn_s_barrier()
#define SCHED() __builtin_amdgcn_sched_barrier(0)
#define LGKM0() asm volatile("s_waitcnt lgkmcnt(0)" ::: "memory")

// ---- m201-style stage: one region (256 rows x 32 cols fp16 = 16KB) = 2 gload units.
// LDS linear; LDS chunk-slot c of row r holds global 16B-chunk (c ^ ((r>>1)&3)).
// REG: 0=A-ks0, 1=A-ks1, 2=B-ks0, 3=B-ks1 at REG*8192 halfs within buffer.
#if HAS_GLLDS
#define STG2(BUF, REG, SRC, ROWBASE, TK, KS)                                         \
  { _Pragma("unroll") for (int u_ = 0; u_ < 2; u_++) {                               \
      int row_ = u_ * 128 + wave * 16 + (lane >> 2);                                 \
      int c_ = lane & 3;                                                             \
      const u16* gp_ = (SRC) + (size_t)((ROWBASE) + row_) * 1024 + (TK) * 64         \
                        + (KS) * 32 + ((c_ ^ ((row_ >> 1) & 3)) * 8);                \
      __builtin_amdgcn_global_load_lds(                                              \
        (const __attribute__((address_space(1))) unsigned int*)gp_,                  \
        (__attribute__((address_space(3))) unsigned int*)(sm + (BUF) * 32768 +       \
          (REG) * 8192 + (u_ * 512 + wave * 64) * 8), 16, 0, 0); } }
#else
#define STG2(BUF, REG, SRC, ROWBASE, TK, KS)                                         \
  { _Pragma("unroll") for (int u_ = 0; u_ < 2; u_++) {                               \
      int row_ = u_ * 128 + wave * 16 + (lane >> 2);                                 \
      int c_ = lane & 3;                                                             \
      const u16* gp_ = (SRC) + (size_t)((ROWBASE) + row_) * 1024 + (TK) * 64         \
                        + (KS) * 32 + ((c_ ^ ((row_ >> 1) & 3)) * 8);                \
      *(u16x8*)(sm + (BUF) * 32768 + (REG) * 8192 + (u_ * 512 + wave * 64 + lane) * 8) \
          = *(const u16x8*)gp_; } }
#endif

// ---- 256^2 (r7) staging for k_gemm_out: [256][32] tile, 4 units of 8KB ----
#if HAS_GLLDS
#define STG(BUF, U, SRC, ROWBASE, KK)                                                \
  { int rl_ = wave * 16 + (lane >> 2);                                               \
    int c_ = lane & 3;                                                               \
    int grow_ = (((U) & 1) * 128) + rl_;                                             \
    const u16* gp_ = (SRC) + (size_t)((ROWBASE) + grow_) * 1024 + (KK)               \
                     + ((c_ ^ ((rl_ >> 1) & 3)) * 8);                                \
    __builtin_amdgcn_global_load_lds(                                                \
        (const __attribute__((address_space(1))) unsigned int*)gp_,                  \
        (__attribute__((address_space(3))) unsigned int*)(sm + (BUF) * 16384 +       \
            (U) * 4096 + wave * 512), 16, 0, 0); }
#else
#define STG(BUF, U, SRC, ROWBASE, KK)                                                \
  { int rl_ = wave * 16 + (lane >> 2);                                               \
    int c_ = lane & 3;                                                               \
    int grow_ = (((U) & 1) * 128) + rl_;                                             \
    const u16* gp_ = (SRC) + (size_t)((ROWBASE) + grow_) * 1024 + (KK)               \
                     + ((c_ ^ ((rl_ >> 1) & 3)) * 8);                                \
    *(u16x8*)(sm + (BUF) * 16384 + (U) * 4096 + wave * 512 + lane * 8)               \
        = *(const u16x8*)gp_; }
#endif

// ---------------- converts ----------------
__global__ __launch_bounds__(256) void k_half(const float* __restrict__ s, u16* __restrict__ d) {
    size_t i = ((size_t)blockIdx.x * 256 + threadIdx.x) * 4;
    f32x4 v = *(const f32x4*)(s + i);
    u16x4 h;
#pragma unroll
    for (int j = 0; j < 4; j++) h[j] = f2h(v[j]);
    *(u16x4*)(d + i) = h;
}

// merged W converts: y selects Wq/Wk/Wv/Wo; dst = Wc..(Wof contiguous after)
__global__ __launch_bounds__(256) void k_halfw(const float* __restrict__ a, const float* __restrict__ b,
                                               const float* __restrict__ c, const float* __restrict__ d2,
                                               u16* __restrict__ o) {
    int y = blockIdx.y;
    const float* src = (y == 0) ? a : (y == 1) ? b : (y == 2) ? c : d2;
    size_t i = ((size_t)blockIdx.x * 256 + threadIdx.x) * 4;
    f32x4 v = *(const f32x4*)(src + i);
    u16x4 h;
#pragma unroll
    for (int j = 0; j < 4; j++) h[j] = f2h(v[j]);
    *(u16x4*)(o + (size_t)y * 1048576 + i) = h;
}

// wt[m*64+d] = omega[d*256+m] * DH^-0.25 (fp16)
__global__ __launch_bounds__(256) void k_omega(const float* __restrict__ om, u16* __restrict__ wh) {
    int i = blockIdx.x * 256 + threadIdx.x; // 16384
    int m = i >> 6, d = i & 63;
    wh[i] = f2h(om[d * 256 + m] * 0.35355339059327373f);
}

__global__ __launch_bounds__(256) void k_zero(float* __restrict__ p, int n) {
    int i = (blockIdx.x * 256 + threadIdx.x) * 4;
    if (i < n) { f32x4 z; z[0]=0.f; z[1]=0.f; z[2]=0.f; z[3]=0.f; *(f32x4*)(p + i) = z; }
}

// ---------------- QKV GEMM: 256x256, BK=64, m201 8-phase, counted vmcnt ----------------
__global__ __launch_bounds__(512, 1) void k_gemm_qkv(
    const u16* __restrict__ Ax, const u16* __restrict__ Bw,
    u16* __restrict__ QK, u16* __restrict__ Vb) {
    __shared__ __align__(16) u16 sm[65536]; // 128 KB: 2 buf x (A 256x64 | B 256x64)
    const int tid = threadIdx.x, wave = tid >> 6, lane = tid & 63;
    const int lr = lane & 15, lkq = lane >> 4;
    const int wr = wave >> 2, wc = wave & 3;
    const int m0 = blockIdx.y * 256, n0 = blockIdx.x * 256;
    const int sec = n0 >> 10;

    // swz invariant under +16-row steps, so frag offsets are base + fm*512 (+ks*8192)
    const int arow = wr * 128 + lr;
    const int aBase = arow * 32 + ((lkq ^ ((arow >> 1) & 3)) * 8);
    const int brow = wc * 64 + lr;
    const int bBase = 16384 + brow * 32 + ((lkq ^ ((brow >> 1) & 3)) * 8);

    f32x4 acc[8][4];
#pragma unroll
    for (int i = 0; i < 8; i++)
#pragma unroll
        for (int j = 0; j < 4; j++)
#pragma unroll
            for (int r = 0; r < 4; r++) acc[i][j][r] = 0.f;

    // prologue: tile 0, issue order A-ks0, B-ks0, A-ks1, B-ks1 -> vmcnt(4) leaves ks1 flying
    STG2(0, 0, Ax, m0, 0, 0)
    STG2(0, 2, Bw, n0, 0, 0)
    STG2(0, 1, Ax, m0, 0, 1)
    STG2(0, 3, Bw, n0, 0, 1)
    asm volatile("s_waitcnt vmcnt(4)" ::: "memory");
    SCHED(); SBAR(); SCHED();

    f16x8 bfr[2][4], afr[4];
    for (int t = 0; t < 16; ++t) {
        const u16* bp = sm + (t & 1) * 32768;
        const int nb = (t + 1) & 1;
        const bool st = t < 15;
        // ---- p0: A(fm0-3) ks0 + B ks0 reads; stage A-ks0(t+1); 16 MFMA ----
#pragma unroll
        for (int f = 0; f < 4; f++) afr[f] = *(const f16x8*)&bp[aBase + f * 512];
#pragma unroll
        for (int j = 0; j < 4; j++) bfr[0][j] = *(const f16x8*)&bp[bBase + j * 512];
        if (st) STG2(nb, 0, Ax, m0, t + 1, 0)
        SBAR(); LGKM0(); SCHED();
        __builtin_amdgcn_s_setprio(1);
#pragma unroll
        for (int i = 0; i < 4; i++)
#pragma unroll
            for (int j = 0; j < 4; j++)
                acc[i][j] = mfma16h(afr[i], bfr[0][j], acc[i][j]);
        __builtin_amdgcn_s_setprio(0);
        SCHED();
        if (st) { asm volatile("s_waitcnt vmcnt(2)" ::: "memory"); }
        else    { asm volatile("s_waitcnt vmcnt(0)" ::: "memory"); }
        SCHED(); SBAR(); SCHED();
        // ---- p1: A(fm0-3) ks1 + B ks1 reads; stage B-ks0(t+1); 16 MFMA ----
#pragma unroll
        for (int f = 0; f < 4; f++) afr[f] = *(const f16x8*)&bp[aBase + 8192 + f * 512];
#pragma unroll
        for (int j = 0; j < 4; j++) bfr[1][j] = *(const f16x8*)&bp[bBase + 8192 + j * 512];
        if (st) STG2(nb, 2, Bw, n0, t + 1, 0)
        SBAR(); LGKM0(); SCHED();
        __builtin_amdgcn_s_setprio(1);
#pragma unroll
        for (int i = 0; i < 4; i++)
#pragma unroll
            for (int j = 0; j < 4; j++)
                acc[i][j] = mfma16h(afr[i], bfr[1][j], acc[i][j]);
        __builtin_amdgcn_s_setprio(0);
        SCHED(); SBAR(); SCHED();
        // ---- p2: A(fm4-7) ks0 reads (B ks0 in regs); stage A-ks1(t+1); 16 MFMA ----
#pragma unroll
        for (int f = 0; f < 4; f++) afr[f] = *(const f16x8*)&bp[aBase + 2048 + f * 512];
        if (st) STG2(nb, 1, Ax, m0, t + 1, 1)
        SBAR(); LGKM0(); SCHED();
        __builtin_amdgcn_s_setprio(1);
#pragma unroll
        for (int i = 0; i < 4; i++)
#pragma unroll
            for (int j = 0; j < 4; j++)
                acc[4 + i][j] = mfma16h(afr[i], bfr[0][j], acc[4 + i][j]);
        __builtin_amdgcn_s_setprio(0);
        SCHED(); SBAR(); SCHED();
        // ---- p3: A(fm4-7) ks1 reads; stage B-ks1(t+1); 16 MFMA; vmcnt(4) ----
#pragma unroll
        for (int f = 0; f < 4; f++) afr[f] = *(const f16x8*)&bp[aBase + 8192 + 2048 + f * 512];
        if (st) STG2(nb, 3, Bw, n0, t + 1, 1)
        SBAR(); LGKM0(); SCHED();
        __builtin_amdgcn_s_setprio(1);
#pragma unroll
        for (int i = 0; i < 4; i++)
#pragma unroll
            for (int j = 0; j < 4; j++)
                acc[4 + i][j] = mfma16h(afr[i], bfr[1][j], acc[4 + i][j]);
        __builtin_amdgcn_s_setprio(0);
        SCHED();
        if (st) { asm volatile("s_waitcnt vmcnt(4)" ::: "memory"); }
        SCHED(); SBAR(); SCHED();
    }

    // epilogue: 8 groups of 32 rows restaged through LDS, coalesced fp16 stores
    float* ep = (float*)sm; // [32][264] f32
    for (int g = 0; g < 8; g++) {
        __syncthreads();
        if (wr == (g >> 2)) {
#pragma unroll
            for (int fi = 0; fi < 2; fi++) {
                int fm = (g & 3) * 2 + fi;
#pragma unroll
                for (int fn = 0; fn < 4; fn++)
#pragma unroll
                    for (int r = 0; r < 4; r++)
                        ep[(fi * 16 + (lane >> 4) * 4 + r) * 264 + wc * 64 + fn * 16 + lr] = acc[fm][fn][r];
            }
        }
        __syncthreads();
        int row = tid >> 4, c0 = (tid & 15) * 16;
        int grow = m0 + g * 32 + row;
        u16x8 h0, h1;
#pragma unroll
        for (int j = 0; j < 8; j++) {
            h0[j] = f2h(ep[row * 264 + c0 + j]);
            h1[j] = f2h(ep[row * 264 + c0 + 8 + j]);
        }
        if (sec < 2) {
            size_t o = (size_t)grow * 2048 + (n0 + c0);
            *(u16x8*)(QK + o) = h0; *(u16x8*)(QK + o + 8) = h1;
        } else {
            size_t o = (size_t)grow * 1024 + (n0 - 2048 + c0);
            *(u16x8*)(Vb + o) = h0; *(u16x8*)(Vb + o + 8) = h1;
        }
    }
}

// ---------------- final GEMM: attn @ Wo^T + bo -> f32 out (r7 256^2 structure) ----------------
__global__ __launch_bounds__(512, 2) void k_gemm_out(
    const u16* __restrict__ Ab, const u16* __restrict__ Bw,
    const float* __restrict__ bias, float* __restrict__ outp) {
    __shared__ __align__(16) u16 sm[32768];
    const int tid = threadIdx.x, wave = tid >> 6, lane = tid & 63;
    const int lr = lane & 15, lkq = lane >> 4;
    const int wr = wave >> 2, wc = wave & 3;
    const int m0 = blockIdx.y * 256, n0 = blockIdx.x * 256;

    int aoff[8], boff[4];
#pragma unroll
    for (int f = 0; f < 8; f++) {
        int row = wr * 128 + f * 16 + lr;
        aoff[f] = row * 32 + ((lkq ^ ((row >> 1) & 3)) * 8);
    }
#pragma unroll
    for (int f = 0; f < 4; f++) {
        int row = wc * 64 + f * 16 + lr;
        boff[f] = row * 32 + ((lkq ^ ((row >> 1) & 3)) * 8);
    }

    f32x4 acc[8][4];
#pragma unroll
    for (int i = 0; i < 8; i++)
#pragma unroll
        for (int j = 0; j < 4; j++)
#pragma unroll
            for (int r = 0; r < 4; r++) acc[i][j][r] = 0.f;

    STG(0, 0, Ab, m0, 0) STG(0, 1, Ab, m0, 0)
    STG(0, 2, Bw, n0, 0) STG(0, 3, Bw, n0, 0)
    asm volatile("s_waitcnt vmcnt(0)" ::: "memory");
    SCHED(); SBAR(); SCHED();

    int cb = 0;
    for (int t = 0; t < 32; ++t) {
        const u16* Abase = sm + cb * 16384;
        const u16* Bbase = Abase + 8192;
        f16x8 afr[4], bfr[4];
#pragma unroll
        for (int f = 0; f < 4; f++) bfr[f] = *(const f16x8*)&Bbase[boff[f]];
#pragma unroll
        for (int f = 0; f < 4; f++) afr[f] = *(const f16x8*)&Abase[aoff[f]];
        if (t < 31) {
            int kk = (t + 1) * 32;
            STG(cb ^ 1, 0, Ab, m0, kk) STG(cb ^ 1, 1, Ab, m0, kk)
            STG(cb ^ 1, 2, Bw, n0, kk) STG(cb ^ 1, 3, Bw, n0, kk)
        }
        SCHED(); SBAR(); LGKM0(); SCHED();
        __builtin_amdgcn_s_setprio(1);
#pragma unroll
        for (int i = 0; i < 4; i++)
#pragma unroll
            for (int j = 0; j < 4; j++)
                acc[i][j] = mfma16h(afr[i], bfr[j], acc[i][j]);
        __builtin_amdgcn_s_setprio(0);
        SCHED(); SBAR(); SCHED();
#pragma unroll
        for (int f = 0; f < 4; f++) afr[f] = *(const f16x8*)&Abase[aoff[4 + f]];
        SCHED(); SBAR(); LGKM0(); SCHED();
        __builtin_amdgcn_s_setprio(1);
#pragma unroll
        for (int i = 0; i < 4; i++)
#pragma unroll
            for (int j = 0; j < 4; j++)
                acc[4 + i][j] = mfma16h(afr[i], bfr[j], acc[4 + i][j]);
        __builtin_amdgcn_s_setprio(0);
        asm volatile("s_waitcnt vmcnt(0)" ::: "memory");
        SCHED(); SBAR(); SCHED();
        cb ^= 1;
    }

    float* ep = (float*)sm; // [32][264]
    for (int g = 0; g < 8; g++) {
        __syncthreads();
        if (wr == (g >> 2)) {
#pragma unroll
            for (int fi = 0; fi < 2; fi++) {
                int fm = (g & 3) * 2 + fi;
#pragma unroll
                for (int fn = 0; fn < 4; fn++)
#pragma unroll
                    for (int r = 0; r < 4; r++)
                        ep[(fi * 16 + (lane >> 4) * 4 + r) * 264 + wc * 64 + fn * 16 + lr] = acc[fm][fn][r];
            }
        }
        __syncthreads();
        int row = tid >> 4, c0 = (tid & 15) * 16;
        int grow = m0 + g * 32 + row;
        float vv[16];
#pragma unroll
        for (int j = 0; j < 16; j++) vv[j] = ep[row * 264 + c0 + j] + bias[n0 + c0 + j];
#pragma unroll
        for (int p = 0; p < 4; p++) {
            f32x4 tv;
#pragma unroll
            for (int q = 0; q < 4; q++) tv[q] = vv[p * 4 + q];
            *(f32x4*)(outp + (size_t)grow * 1024 + n0 + c0 + p * 4) = tv;
        }
    }
}

// ---------------- fused phi(K) + KV + Ksum (fp16; phi(K) scaled by extra 1/16) ----------------
__global__ __launch_bounds__(256) void k_phik_kv(
    const u16* __restrict__ QK, const u16* __restrict__ wt,
    const u16* __restrict__ Vb, float* __restrict__ KVacc, float* __restrict__ Ksum) {
    __shared__ __align__(16) u16 sKh[64 * 72];
    __shared__ __align__(16) u16 sVt[64 * 72];
    __shared__ __align__(16) u16 sKfT[256 * 72];
    __shared__ float snsq[64];
    const int tid = threadIdx.x, wave = tid >> 6, lane = tid & 63;
    const int lr = lane & 15, lk = (lane >> 4) * 8;
    const int kc = blockIdx.x, bh = blockIdx.y;
    const int b = bh >> 4, h = bh & 15;

    f16x8 wb[4][2];
#pragma unroll
    for (int fn = 0; fn < 4; fn++)
#pragma unroll
        for (int ks = 0; ks < 2; ks++)
            wb[fn][ks] = *(const f16x8*)(wt + (size_t)(wave * 64 + fn * 16 + lr) * 64 + ks * 32 + lk);

    f32x4 akv[4][4];
#pragma unroll
    for (int i = 0; i < 4; i++)
#pragma unroll
        for (int j = 0; j < 4; j++)
#pragma unroll
            for (int r = 0; r < 4; r++) akv[i][j][r] = 0.f;
    float ksm[4] = {0.f, 0.f, 0.f, 0.f};

    for (int it = 0; it < 4; it++) {
        int l0 = kc * 256 + it * 64;
        __syncthreads();
        { // stage K + nsq
            int row = tid >> 2, c0 = (tid & 3) * 16;
            size_t g = ((size_t)(b * Ll + l0 + row)) * 2048 + 1024 + h * 64 + c0;
            u16x8 h0 = *(const u16x8*)(QK + g);
            u16x8 h1 = *(const u16x8*)(QK + g + 8);
            *(u16x8*)&sKh[row * 72 + c0]     = h0;
            *(u16x8*)&sKh[row * 72 + c0 + 8] = h1;
            float s = 0.f;
#pragma unroll
            for (int j = 0; j < 8; j++) {
                float a = h2f(h0[j]); s += a * a;
                float c = h2f(h1[j]); s += c * c;
            }
            s += __shfl_xor(s, 1); s += __shfl_xor(s, 2);
            if ((tid & 3) == 0) snsq[row] = s * 0.0625f;
        }
        { // stage V transposed
            int l = tid >> 2, d0 = (tid & 3) * 16;
            size_t g = ((size_t)(b * Ll + l0 + l)) * 1024 + h * 64 + d0;
            u16x8 v0 = *(const u16x8*)(Vb + g);
            u16x8 v1 = *(const u16x8*)(Vb + g + 8);
#pragma unroll
            for (int j = 0; j < 8; j++) {
                sVt[(d0 + j) * 72 + l] = v0[j];
                sVt[(d0 + 8 + j) * 72 + l] = v1[j];
            }
        }
        __syncthreads();
#pragma unroll
        for (int fm = 0; fm < 4; fm++) {
            f32x4 ap[4];
#pragma unroll
            for (int fn = 0; fn < 4; fn++)
#pragma unroll
                for (int r = 0; r < 4; r++) ap[fn][r] = 0.f;
#pragma unroll
            for (int ks = 0; ks < 2; ks++) {
                f16x8 aH = *(const f16x8*)&sKh[(fm * 16 + lr) * 72 + ks * 32 + lk];
#pragma unroll
                for (int fn = 0; fn < 4; fn++)
                    ap[fn] = mfma16h(aH, wb[fn][ks], ap[fn]);
            }
#pragma unroll
            for (int fn = 0; fn < 4; fn++) {
                u16x4 pk;
#pragma unroll
                for (int r = 0; r < 4; r++) {
                    float ns = snsq[fm * 16 + (lane >> 4) * 4 + r];
                    float val = __expf(ap[fn][r] - ns) * 0.00390625f; // 1/256 (extra 1/16 folded)
                    ksm[fn] += val;
                    pk[r] = f2h(val);
                }
                *(u16x4*)&sKfT[(wave * 64 + fn * 16 + lr) * 72 + fm * 16 + (lane >> 4) * 4] = pk;
            }
        }
#pragma unroll
        for (int ks = 0; ks < 2; ks++) {
            f16x8 a4[4], b4[4];
#pragma unroll
            for (int f = 0; f < 4; f++) {
                a4[f] = *(const f16x8*)&sKfT[(wave * 64 + f * 16 + lr) * 72 + ks * 32 + lk];
                b4[f] = *(const f16x8*)&sVt[(f * 16 + lr) * 72 + ks * 32 + lk];
            }
#pragma unroll
            for (int fm = 0; fm < 4; fm++)
#pragma unroll
                for (int fn = 0; fn < 4; fn++)
                    akv[fm][fn] = mfma16h(a4[fm], b4[fn], akv[fm][fn]);
        }
    }
#pragma unroll
    for (int fm = 0; fm < 4; fm++)
#pragma unroll
        for (int fn = 0; fn < 4; fn++)
#pragma unroll
            for (int r = 0; r < 4; r++) {
                int m = wave * 64 + fm * 16 + (lane >> 4) * 4 + r;
                int d = fn * 16 + lr;
                atomicAdd(&KVacc[((size_t)bh << 14) + m * 64 + d], akv[fm][fn][r]);
            }
#pragma unroll
    for (int fn = 0; fn < 4; fn++) {
        ksm[fn] += __shfl_xor(ksm[fn], 16);
        ksm[fn] += __shfl_xor(ksm[fn], 32);
    }
    if (lane < 16) {
#pragma unroll
        for (int fn = 0; fn < 4; fn++)
            atomicAdd(&Ksum[bh * 256 + wave * 64 + fn * 16 + lane], ksm[fn]);
    }
}

// KVt[bh][d][m] = fp16(KVacc[bh][m][d])
__global__ __launch_bounds__(256) void k_kvt(const float* __restrict__ KVacc, u16* __restrict__ KVt) {
    int i = blockIdx.x * 256 + threadIdx.x;
    int bh = i >> 14, dd = (i >> 8) & 63, m = i & 255;
    KVt[i] = f2h(KVacc[((size_t)bh << 14) + m * 64 + dd]);
}

// ---------------- fused phi(Q) + norm + attn (fp16) ----------------
__global__ __launch_bounds__(512) void k_phiq_attn(
    const u16* __restrict__ QK, const u16* __restrict__ wt,
    const u16* __restrict__ KVt, const float* __restrict__ Ksum,
    u16* __restrict__ attn) {
    __shared__ __align__(16) u16 sQh[64 * 72];
    __shared__ __align__(16) u16 sQf[64 * 264];
    __shared__ float sKs[256];
    __shared__ float snsq[64];
    __shared__ float snorm[64];
    const int tid = threadIdx.x, wave = tid >> 6, lane = tid & 63;
    const int lr = lane & 15, lk = (lane >> 4) * 8;
    const int bh = blockIdx.y, b = bh >> 4, h = bh & 15;
    const int mq = wave & 3;
    const int lh = wave >> 2;
    const int af = wave & 3;
    const int ad = wave >> 2;

    f16x8 wb[4][2];
#pragma unroll
    for (int fn = 0; fn < 4; fn++)
#pragma unroll
        for (int ks = 0; ks < 2; ks++)
            wb[fn][ks] = *(const f16x8*)(wt + (size_t)(mq * 64 + fn * 16 + lr) * 64 + ks * 32 + lk);
    f16x8 kvb[2][8];
#pragma unroll
    for (int fn = 0; fn < 2; fn++)
#pragma unroll
        for (int ks = 0; ks < 8; ks++)
            kvb[fn][ks] = *(const f16x8*)(KVt + ((size_t)bh << 14) +
                                          (size_t)(ad * 32 + fn * 16 + lr) * 256 + ks * 32 + lk);
    if (tid < 256) sKs[tid] = Ksum[bh * 256 + tid];

    for (int st = 0; st < 2; st++) {
        const int l0 = (blockIdx.x * 2 + st) * 64;
        __syncthreads();
        {
            int row = tid >> 3, c0 = (tid & 7) * 8;
            size_t g = ((size_t)(b * Ll + l0 + row)) * 2048 + h * 64 + c0;
            u16x8 vh = *(const u16x8*)(QK + g);
            *(u16x8*)&sQh[row * 72 + c0] = vh;
            float s = 0.f;
#pragma unroll
            for (int j = 0; j < 8; j++) { float a = h2f(vh[j]); s += a * a; }
            s += __shfl_xor(s, 1); s += __shfl_xor(s, 2); s += __shfl_xor(s, 4);
            if ((tid & 7) == 0) snsq[row] = s * 0.0625f;
        }
        __syncthreads();
#pragma unroll
        for (int fm = 0; fm < 2; fm++) {
            f32x4 ap[4];
#pragma unroll
            for (int fn = 0; fn < 4; fn++)
#pragma unroll
                for (int r = 0; r < 4; r++) ap[fn][r] = 0.f;
#pragma unroll
            for (int ks = 0; ks < 2; ks++) {
                f16x8 aH = *(const f16x8*)&sQh[(lh * 32 + fm * 16 + lr) * 72 + ks * 32 + lk];
#pragma unroll
                for (int fn = 0; fn < 4; fn++)
                    ap[fn] = mfma16h(aH, wb[fn][ks], ap[fn]);
            }
#pragma unroll
            for (int fn = 0; fn < 4; fn++)
#pragma unroll
                for (int r = 0; r < 4; r++) {
                    int l = lh * 32 + fm * 16 + (lane >> 4) * 4 + r;
                    int m = mq * 64 + fn * 16 + lr;
                    sQf[l * 264 + m] = f2h(__expf(ap[fn][r] - snsq[l]) * 0.0625f);
                }
        }
        __syncthreads();
        { // norm[l] = sum_m Qf * Ksum, vectorized LDS reads
            int l = tid >> 3, m0 = (tid & 7) * 32;
            float s = 0.f;
#pragma unroll
            for (int j4 = 0; j4 < 4; j4++) {
                u16x8 qv = *(const u16x8*)&sQf[l * 264 + m0 + j4 * 8];
#pragma unroll
                for (int j = 0; j < 8; j++) s += h2f(qv[j]) * sKs[m0 + j4 * 8 + j];
            }
            s += __shfl_xor(s, 1); s += __shfl_xor(s, 2); s += __shfl_xor(s, 4);
            if ((tid & 7) == 0) snorm[l] = s;
        }
        f32x4 aa[2];
#pragma unroll
        for (int fn = 0; fn < 2; fn++)
#pragma unroll
            for (int r = 0; r < 4; r++) aa[fn][r] = 0.f;
#pragma unroll
        for (int ks = 0; ks < 8; ks++) {
            f16x8 a = *(const f16x8*)&sQf[(af * 16 + lr) * 264 + ks * 32 + lk];
            aa[0] = mfma16h(a, kvb[0][ks], aa[0]);
            aa[1] = mfma16h(a, kvb[1][ks], aa[1]);
        }
        __syncthreads();
        float* ep = (float*)sQf; // [64][68]
#pragma unroll
        for (int fn = 0; fn < 2; fn++)
#pragma unroll
            for (int r = 0; r < 4; r++) {
                int l = af * 16 + (lane >> 4) * 4 + r;
                int d = ad * 32 + fn * 16 + lr;
                ep[l * 68 + d] = aa[fn][r];
            }
        __syncthreads();
        {
            int l = tid >> 3, d0 = (tid & 7) * 8;
            // norm carries 1/16 from phi(K) extra scale: clamp = 1e-6/16
            float inv = 1.0f / fmaxf(snorm[l], 6.25e-8f);
            u16x8 o;
#pragma unroll
            for (int j = 0; j < 8; j++) o[j] = f2h(ep[l * 68 + d0 + j] * inv);
            *(u16x8*)(attn + ((size_t)(b * Ll + l0 + l)) * 1024 + h * 64 + d0) = o;
        }
    }
}

extern "C" void kernel_launch(void* const* d_in, const int* in_sizes, int n_in,
                              void* d_out, int out_size, void* d_ws, size_t ws_size,
                              hipStream_t stream) {
    (void)in_sizes; (void)n_in; (void)out_size; (void)ws_size;
    const float* x  = (const float*)d_in[0];
    const float* Wq = (const float*)d_in[1];
    const float* Wk = (const float*)d_in[2];
    const float* Wv = (const float*)d_in[3];
    const float* Wo = (const float*)d_in[4];
    const float* bo = (const float*)d_in[5];
    const float* om = (const float*)d_in[6];

    char* w = (char*)d_ws;
    size_t o = 0;
    auto take = [&](size_t n) { char* p = w + o; o += n; return p; };
    u16* QK  = (u16*)take(67108864);   // [16384][2048] fp16: Q | K
    u16* Vb  = (u16*)take(33554432);   // [16384][1024] fp16
    u16* xh  = (u16*)take(33554432);   // x fp16
    u16* Wc  = (u16*)take(6291456);    // Wq|Wk|Wv fp16 [3072][1024]
    u16* Wof = (u16*)take(2097152);    // Wo fp16 (contiguous after Wc for k_halfw)
    u16* wt  = (u16*)take(32768);      // omega^T scaled fp16 [256][64]
    float* KVacc = (float*)take(4194304);
    float* Ksum  = (float*)take(65536);  // contiguous after KVacc for k_zero
    u16* KVt = (u16*)take(2097152);
    u16* attn = Vb; // alias: V dead after k_phik_kv

    k_half<<<16384, 256, 0, stream>>>(x, xh);
    k_halfw<<<dim3(1024, 4), 256, 0, stream>>>(Wq, Wk, Wv, Wo, Wc);
    k_omega<<<64, 256, 0, stream>>>(om, wt);
    k_zero<<<1040, 256, 0, stream>>>(KVacc, 1064960); // KVacc + Ksum

    k_gemm_qkv<<<dim3(12, 64), 512, 0, stream>>>(xh, Wc, QK, Vb);
    k_phik_kv<<<dim3(16, 64), 256, 0, stream>>>(QK, wt, Vb, KVacc, Ksum);
    k_kvt<<<4096, 256, 0, stream>>>(KVacc, KVt);
    k_phiq_attn<<<dim3(32, 64), 512, 0, stream>>>(QK, wt, KVt, Ksum, attn);
    k_gemm_out<<<dim3(4, 64), 512, 0, stream>>>(attn, Wof, bo, (float*)d_out);
}

// Round 9
// 369.648 us; speedup vs baseline: 1.1172x; 1.0995x over previous
//
#include <hip/hip_runtime.h>

typedef unsigned short u16;
typedef __attribute__((ext_vector_type(4))) float f32x4;
typedef _Float16 f16x8 __attribute__((ext_vector_type(8)));
typedef __attribute__((ext_vector_type(4))) u16   u16x4;
typedef __attribute__((ext_vector_type(8))) u16   u16x8;

#define DEV static __device__ __forceinline__

constexpr int Ll = 4096;

DEV float h2f(u16 v) { _Float16 h; __builtin_memcpy(&h, &v, 2); return (float)h; }
DEV u16 f2h(float f) { _Float16 h = (_Float16)f; u16 u; __builtin_memcpy(&u, &h, 2); return u; }

DEV f32x4 mfma16h(f16x8 a, f16x8 b, f32x4 c) {
    return __builtin_amdgcn_mfma_f32_16x16x32_f16(a, b, c, 0, 0, 0);
}

#if defined(__has_builtin)
#if __has_builtin(__builtin_amdgcn_global_load_lds)
#define HAS_GLLDS 1
#endif
#endif
#ifndef HAS_GLLDS
#define HAS_GLLDS 0
#endif

#define SBAR()  __builtin_amdgcn_s_barrier()
#define SCHED() __builtin_amdgcn_sched_barrier(0)
#define LGKM0() asm volatile("s_waitcnt lgkmcnt(0)" ::: "memory")

// ---- m201-style stage: one region (256 rows x 32 cols fp16 = 16KB) = 2 gload units.
#if HAS_GLLDS
#define STG2(BUF, REG, SRC, ROWBASE, TK, KS)                                         \
  { _Pragma("unroll") for (int u_ = 0; u_ < 2; u_++) {                               \
      int row_ = u_ * 128 + wave * 16 + (lane >> 2);                                 \
      int c_ = lane & 3;                                                             \
      const u16* gp_ = (SRC) + (size_t)((ROWBASE) + row_) * 1024 + (TK) * 64         \
                        + (KS) * 32 + ((c_ ^ ((row_ >> 1) & 3)) * 8);                \
      __builtin_amdgcn_global_load_lds(                                              \
        (const __attribute__((address_space(1))) unsigned int*)gp_,                  \
        (__attribute__((address_space(3))) unsigned int*)(sm + (BUF) * 32768 +       \
          (REG) * 8192 + (u_ * 512 + wave * 64) * 8), 16, 0, 0); } }
#else
#define STG2(BUF, REG, SRC, ROWBASE, TK, KS)                                         \
  { _Pragma("unroll") for (int u_ = 0; u_ < 2; u_++) {                               \
      int row_ = u_ * 128 + wave * 16 + (lane >> 2);                                 \
      int c_ = lane & 3;                                                             \
      const u16* gp_ = (SRC) + (size_t)((ROWBASE) + row_) * 1024 + (TK) * 64         \
                        + (KS) * 32 + ((c_ ^ ((row_ >> 1) & 3)) * 8);                \
      *(u16x8*)(sm + (BUF) * 32768 + (REG) * 8192 + (u_ * 512 + wave * 64 + lane) * 8) \
          = *(const u16x8*)gp_; } }
#endif

// ---- 256^2 staging for k_gemm_out: [256][32] tile, 4 units of 8KB ----
#if HAS_GLLDS
#define STG(BUF, U, SRC, ROWBASE, KK)                                                \
  { int rl_ = wave * 16 + (lane >> 2);                                               \
    int c_ = lane & 3;                                                               \
    int grow_ = (((U) & 1) * 128) + rl_;                                             \
    const u16* gp_ = (SRC) + (size_t)((ROWBASE) + grow_) * 1024 + (KK)               \
                     + ((c_ ^ ((rl_ >> 1) & 3)) * 8);                                \
    __builtin_amdgcn_global_load_lds(                                                \
        (const __attribute__((address_space(1))) unsigned int*)gp_,                  \
        (__attribute__((address_space(3))) unsigned int*)(sm + (BUF) * 16384 +       \
            (U) * 4096 + wave * 512), 16, 0, 0); }
#else
#define STG(BUF, U, SRC, ROWBASE, KK)                                                \
  { int rl_ = wave * 16 + (lane >> 2);                                               \
    int c_ = lane & 3;                                                               \
    int grow_ = (((U) & 1) * 128) + rl_;                                             \
    const u16* gp_ = (SRC) + (size_t)((ROWBASE) + grow_) * 1024 + (KK)               \
                     + ((c_ ^ ((rl_ >> 1) & 3)) * 8);                                \
    *(u16x8*)(sm + (BUF) * 16384 + (U) * 4096 + wave * 512 + lane * 8)               \
        = *(const u16x8*)gp_; }
#endif

// ---------------- merged prep: x, Wq|Wk|Wv|Wo, omega ----------------
__global__ __launch_bounds__(256) void k_prep(
    const float* __restrict__ x, const float* __restrict__ Wq, const float* __restrict__ Wk,
    const float* __restrict__ Wv, const float* __restrict__ Wo, const float* __restrict__ om,
    u16* __restrict__ xh, u16* __restrict__ Wc, u16* __restrict__ wtp) {
    int bx = blockIdx.x, tid = threadIdx.x;
    if (bx < 16384) {
        size_t i = ((size_t)bx * 256 + tid) * 4;
        f32x4 v = *(const f32x4*)(x + i);
        u16x4 h;
#pragma unroll
        for (int j = 0; j < 4; j++) h[j] = f2h(v[j]);
        *(u16x4*)(xh + i) = h;
    } else if (bx < 20480) {
        int wsel = (bx - 16384) >> 10;
        const float* src = (wsel == 0) ? Wq : (wsel == 1) ? Wk : (wsel == 2) ? Wv : Wo;
        size_t i = ((size_t)((bx - 16384) & 1023) * 256 + tid) * 4;
        f32x4 v = *(const f32x4*)(src + i);
        u16x4 h;
#pragma unroll
        for (int j = 0; j < 4; j++) h[j] = f2h(v[j]);
        *(u16x4*)(Wc + (size_t)wsel * 1048576 + i) = h;
    } else {
        int i = (bx - 20480) * 256 + tid; // 16384
        int m = i >> 6, d = i & 63;
        wtp[i] = f2h(om[d * 256 + m] * 0.35355339059327373f);
    }
}

// ---------------- QKV GEMM: 256x256, BK=64, 8-phase, counted vmcnt (r8, frozen) ----------------
__global__ __launch_bounds__(512, 1) void k_gemm_qkv(
    const u16* __restrict__ Ax, const u16* __restrict__ Bw,
    u16* __restrict__ QK, u16* __restrict__ Vb) {
    __shared__ __align__(16) u16 sm[65536]; // 128 KB
    const int tid = threadIdx.x, wave = tid >> 6, lane = tid & 63;
    const int lr = lane & 15, lkq = lane >> 4;
    const int wr = wave >> 2, wc = wave & 3;
    const int m0 = blockIdx.y * 256, n0 = blockIdx.x * 256;
    const int sec = n0 >> 10;

    const int arow = wr * 128 + lr;
    const int aBase = arow * 32 + ((lkq ^ ((arow >> 1) & 3)) * 8);
    const int brow = wc * 64 + lr;
    const int bBase = 16384 + brow * 32 + ((lkq ^ ((brow >> 1) & 3)) * 8);

    f32x4 acc[8][4];
#pragma unroll
    for (int i = 0; i < 8; i++)
#pragma unroll
        for (int j = 0; j < 4; j++)
#pragma unroll
            for (int r = 0; r < 4; r++) acc[i][j][r] = 0.f;

    STG2(0, 0, Ax, m0, 0, 0)
    STG2(0, 2, Bw, n0, 0, 0)
    STG2(0, 1, Ax, m0, 0, 1)
    STG2(0, 3, Bw, n0, 0, 1)
    asm volatile("s_waitcnt vmcnt(4)" ::: "memory");
    SCHED(); SBAR(); SCHED();

    f16x8 bfr[2][4], afr[4];
    for (int t = 0; t < 16; ++t) {
        const u16* bp = sm + (t & 1) * 32768;
        const int nb = (t + 1) & 1;
        const bool st = t < 15;
#pragma unroll
        for (int f = 0; f < 4; f++) afr[f] = *(const f16x8*)&bp[aBase + f * 512];
#pragma unroll
        for (int j = 0; j < 4; j++) bfr[0][j] = *(const f16x8*)&bp[bBase + j * 512];
        if (st) STG2(nb, 0, Ax, m0, t + 1, 0)
        SBAR(); LGKM0(); SCHED();
        __builtin_amdgcn_s_setprio(1);
#pragma unroll
        for (int i = 0; i < 4; i++)
#pragma unroll
            for (int j = 0; j < 4; j++)
                acc[i][j] = mfma16h(afr[i], bfr[0][j], acc[i][j]);
        __builtin_amdgcn_s_setprio(0);
        SCHED();
        if (st) { asm volatile("s_waitcnt vmcnt(2)" ::: "memory"); }
        else    { asm volatile("s_waitcnt vmcnt(0)" ::: "memory"); }
        SCHED(); SBAR(); SCHED();
#pragma unroll
        for (int f = 0; f < 4; f++) afr[f] = *(const f16x8*)&bp[aBase + 8192 + f * 512];
#pragma unroll
        for (int j = 0; j < 4; j++) bfr[1][j] = *(const f16x8*)&bp[bBase + 8192 + j * 512];
        if (st) STG2(nb, 2, Bw, n0, t + 1, 0)
        SBAR(); LGKM0(); SCHED();
        __builtin_amdgcn_s_setprio(1);
#pragma unroll
        for (int i = 0; i < 4; i++)
#pragma unroll
            for (int j = 0; j < 4; j++)
                acc[i][j] = mfma16h(afr[i], bfr[1][j], acc[i][j]);
        __builtin_amdgcn_s_setprio(0);
        SCHED(); SBAR(); SCHED();
#pragma unroll
        for (int f = 0; f < 4; f++) afr[f] = *(const f16x8*)&bp[aBase + 2048 + f * 512];
        if (st) STG2(nb, 1, Ax, m0, t + 1, 1)
        SBAR(); LGKM0(); SCHED();
        __builtin_amdgcn_s_setprio(1);
#pragma unroll
        for (int i = 0; i < 4; i++)
#pragma unroll
            for (int j = 0; j < 4; j++)
                acc[4 + i][j] = mfma16h(afr[i], bfr[0][j], acc[4 + i][j]);
        __builtin_amdgcn_s_setprio(0);
        SCHED(); SBAR(); SCHED();
#pragma unroll
        for (int f = 0; f < 4; f++) afr[f] = *(const f16x8*)&bp[aBase + 8192 + 2048 + f * 512];
        if (st) STG2(nb, 3, Bw, n0, t + 1, 1)
        SBAR(); LGKM0(); SCHED();
        __builtin_amdgcn_s_setprio(1);
#pragma unroll
        for (int i = 0; i < 4; i++)
#pragma unroll
            for (int j = 0; j < 4; j++)
                acc[4 + i][j] = mfma16h(afr[i], bfr[1][j], acc[4 + i][j]);
        __builtin_amdgcn_s_setprio(0);
        SCHED();
        if (st) { asm volatile("s_waitcnt vmcnt(4)" ::: "memory"); }
        SCHED(); SBAR(); SCHED();
    }

    float* ep = (float*)sm; // [32][264]
    for (int g = 0; g < 8; g++) {
        __syncthreads();
        if (wr == (g >> 2)) {
#pragma unroll
            for (int fi = 0; fi < 2; fi++) {
                int fm = (g & 3) * 2 + fi;
#pragma unroll
                for (int fn = 0; fn < 4; fn++)
#pragma unroll
                    for (int r = 0; r < 4; r++)
                        ep[(fi * 16 + (lane >> 4) * 4 + r) * 264 + wc * 64 + fn * 16 + lr] = acc[fm][fn][r];
            }
        }
        __syncthreads();
        int row = tid >> 4, c0 = (tid & 15) * 16;
        int grow = m0 + g * 32 + row;
        u16x8 h0, h1;
#pragma unroll
        for (int j = 0; j < 8; j++) {
            h0[j] = f2h(ep[row * 264 + c0 + j]);
            h1[j] = f2h(ep[row * 264 + c0 + 8 + j]);
        }
        if (sec < 2) {
            size_t o = (size_t)grow * 2048 + (n0 + c0);
            *(u16x8*)(QK + o) = h0; *(u16x8*)(QK + o + 8) = h1;
        } else {
            size_t o = (size_t)grow * 1024 + (n0 - 2048 + c0);
            *(u16x8*)(Vb + o) = h0; *(u16x8*)(Vb + o + 8) = h1;
        }
    }
}

// ---------------- final GEMM: attn @ Wo^T + bo -> f32 out (r7 structure, frozen) ----------------
__global__ __launch_bounds__(512, 2) void k_gemm_out(
    const u16* __restrict__ Ab, const u16* __restrict__ Bw,
    const float* __restrict__ bias, float* __restrict__ outp) {
    __shared__ __align__(16) u16 sm[32768];
    const int tid = threadIdx.x, wave = tid >> 6, lane = tid & 63;
    const int lr = lane & 15, lkq = lane >> 4;
    const int wr = wave >> 2, wc = wave & 3;
    const int m0 = blockIdx.y * 256, n0 = blockIdx.x * 256;

    int aoff[8], boff[4];
#pragma unroll
    for (int f = 0; f < 8; f++) {
        int row = wr * 128 + f * 16 + lr;
        aoff[f] = row * 32 + ((lkq ^ ((row >> 1) & 3)) * 8);
    }
#pragma unroll
    for (int f = 0; f < 4; f++) {
        int row = wc * 64 + f * 16 + lr;
        boff[f] = row * 32 + ((lkq ^ ((row >> 1) & 3)) * 8);
    }

    f32x4 acc[8][4];
#pragma unroll
    for (int i = 0; i < 8; i++)
#pragma unroll
        for (int j = 0; j < 4; j++)
#pragma unroll
            for (int r = 0; r < 4; r++) acc[i][j][r] = 0.f;

    STG(0, 0, Ab, m0, 0) STG(0, 1, Ab, m0, 0)
    STG(0, 2, Bw, n0, 0) STG(0, 3, Bw, n0, 0)
    asm volatile("s_waitcnt vmcnt(0)" ::: "memory");
    SCHED(); SBAR(); SCHED();

    int cb = 0;
    for (int t = 0; t < 32; ++t) {
        const u16* Abase = sm + cb * 16384;
        const u16* Bbase = Abase + 8192;
        f16x8 afr[4], bfr[4];
#pragma unroll
        for (int f = 0; f < 4; f++) bfr[f] = *(const f16x8*)&Bbase[boff[f]];
#pragma unroll
        for (int f = 0; f < 4; f++) afr[f] = *(const f16x8*)&Abase[aoff[f]];
        if (t < 31) {
            int kk = (t + 1) * 32;
            STG(cb ^ 1, 0, Ab, m0, kk) STG(cb ^ 1, 1, Ab, m0, kk)
            STG(cb ^ 1, 2, Bw, n0, kk) STG(cb ^ 1, 3, Bw, n0, kk)
        }
        SCHED(); SBAR(); LGKM0(); SCHED();
        __builtin_amdgcn_s_setprio(1);
#pragma unroll
        for (int i = 0; i < 4; i++)
#pragma unroll
            for (int j = 0; j < 4; j++)
                acc[i][j] = mfma16h(afr[i], bfr[j], acc[i][j]);
        __builtin_amdgcn_s_setprio(0);
        SCHED(); SBAR(); SCHED();
#pragma unroll
        for (int f = 0; f < 4; f++) afr[f] = *(const f16x8*)&Abase[aoff[4 + f]];
        SCHED(); SBAR(); LGKM0(); SCHED();
        __builtin_amdgcn_s_setprio(1);
#pragma unroll
        for (int i = 0; i < 4; i++)
#pragma unroll
            for (int j = 0; j < 4; j++)
                acc[4 + i][j] = mfma16h(afr[i], bfr[j], acc[4 + i][j]);
        __builtin_amdgcn_s_setprio(0);
        asm volatile("s_waitcnt vmcnt(0)" ::: "memory");
        SCHED(); SBAR(); SCHED();
        cb ^= 1;
    }

    float* ep = (float*)sm; // [32][264]
    for (int g = 0; g < 8; g++) {
        __syncthreads();
        if (wr == (g >> 2)) {
#pragma unroll
            for (int fi = 0; fi < 2; fi++) {
                int fm = (g & 3) * 2 + fi;
#pragma unroll
                for (int fn = 0; fn < 4; fn++)
#pragma unroll
                    for (int r = 0; r < 4; r++)
                        ep[(fi * 16 + (lane >> 4) * 4 + r) * 264 + wc * 64 + fn * 16 + lr] = acc[fm][fn][r];
            }
        }
        __syncthreads();
        int row = tid >> 4, c0 = (tid & 15) * 16;
        int grow = m0 + g * 32 + row;
        float vv[16];
#pragma unroll
        for (int j = 0; j < 16; j++) vv[j] = ep[row * 264 + c0 + j] + bias[n0 + c0 + j];
#pragma unroll
        for (int p = 0; p < 4; p++) {
            f32x4 tv;
#pragma unroll
            for (int q = 0; q < 4; q++) tv[q] = vv[p * 4 + q];
            *(f32x4*)(outp + (size_t)grow * 1024 + n0 + c0 + p * 4) = tv;
        }
    }
}

// ---------------- fused phi(K) + KV + Ksum: kc-slab stores (no atomics), reg prefetch ----------------
__global__ __launch_bounds__(256) void k_phik_kv(
    const u16* __restrict__ QK, const u16* __restrict__ wt,
    const u16* __restrict__ Vb, float* __restrict__ KVacc, float* __restrict__ Ksum) {
    __shared__ __align__(16) u16 sKh[64 * 72];
    __shared__ __align__(16) u16 sVt[64 * 72];
    __shared__ __align__(16) u16 sKfT[256 * 72];
    __shared__ float snsq[64];
    const int tid = threadIdx.x, wave = tid >> 6, lane = tid & 63;
    const int lr = lane & 15, lk = (lane >> 4) * 8;
    const int kc = blockIdx.x, bh = blockIdx.y;
    const int b = bh >> 4, h = bh & 15;

    f16x8 wb[4][2];
#pragma unroll
    for (int fn = 0; fn < 4; fn++)
#pragma unroll
        for (int ks = 0; ks < 2; ks++)
            wb[fn][ks] = *(const f16x8*)(wt + (size_t)(wave * 64 + fn * 16 + lr) * 64 + ks * 32 + lk);

    f32x4 akv[4][4];
#pragma unroll
    for (int i = 0; i < 4; i++)
#pragma unroll
        for (int j = 0; j < 4; j++)
#pragma unroll
            for (int r = 0; r < 4; r++) akv[i][j][r] = 0.f;
    float ksm[4] = {0.f, 0.f, 0.f, 0.f};

    // prefetch regs for iteration 0
    const int rowS = tid >> 2, cS = (tid & 3) * 16;
    size_t gK = ((size_t)(b * Ll + kc * 512 + rowS)) * 2048 + 1024 + h * 64 + cS;
    size_t gV = ((size_t)(b * Ll + kc * 512 + rowS)) * 1024 + h * 64 + cS;
    u16x8 kh0 = *(const u16x8*)(QK + gK);
    u16x8 kh1 = *(const u16x8*)(QK + gK + 8);
    u16x8 vv0 = *(const u16x8*)(Vb + gV);
    u16x8 vv1 = *(const u16x8*)(Vb + gV + 8);

    for (int it = 0; it < 8; it++) {
        __syncthreads();
        { // write K stage + nsq from regs
            *(u16x8*)&sKh[rowS * 72 + cS]     = kh0;
            *(u16x8*)&sKh[rowS * 72 + cS + 8] = kh1;
            float s = 0.f;
#pragma unroll
            for (int j = 0; j < 8; j++) {
                float a = h2f(kh0[j]); s += a * a;
                float c = h2f(kh1[j]); s += c * c;
            }
            s += __shfl_xor(s, 1); s += __shfl_xor(s, 2);
            if ((tid & 3) == 0) snsq[rowS] = s * 0.0625f;
        }
        { // write V transposed from regs
#pragma unroll
            for (int j = 0; j < 8; j++) {
                sVt[(cS + j) * 72 + rowS]     = vv0[j];
                sVt[(cS + 8 + j) * 72 + rowS] = vv1[j];
            }
        }
        __syncthreads();
        if (it < 7) { // issue next-iteration loads; land under MFMA phases
            gK += 131072; gV += 65536;
            kh0 = *(const u16x8*)(QK + gK);
            kh1 = *(const u16x8*)(QK + gK + 8);
            vv0 = *(const u16x8*)(Vb + gV);
            vv1 = *(const u16x8*)(Vb + gV + 8);
        }
#pragma unroll
        for (int fm = 0; fm < 4; fm++) {
            f32x4 ap[4];
#pragma unroll
            for (int fn = 0; fn < 4; fn++)
#pragma unroll
                for (int r = 0; r < 4; r++) ap[fn][r] = 0.f;
#pragma unroll
            for (int ks = 0; ks < 2; ks++) {
                f16x8 aH = *(const f16x8*)&sKh[(fm * 16 + lr) * 72 + ks * 32 + lk];
#pragma unroll
                for (int fn = 0; fn < 4; fn++)
                    ap[fn] = mfma16h(aH, wb[fn][ks], ap[fn]);
            }
#pragma unroll
            for (int fn = 0; fn < 4; fn++) {
                u16x4 pk;
#pragma unroll
                for (int r = 0; r < 4; r++) {
                    float ns = snsq[fm * 16 + (lane >> 4) * 4 + r];
                    float val = __expf(ap[fn][r] - ns) * 0.00390625f; // 1/256
                    ksm[fn] += val;
                    pk[r] = f2h(val);
                }
                *(u16x4*)&sKfT[(wave * 64 + fn * 16 + lr) * 72 + fm * 16 + (lane >> 4) * 4] = pk;
            }
        }
#pragma unroll
        for (int ks = 0; ks < 2; ks++) {
            f16x8 a4[4], b4[4];
#pragma unroll
            for (int f = 0; f < 4; f++) {
                a4[f] = *(const f16x8*)&sKfT[(wave * 64 + f * 16 + lr) * 72 + ks * 32 + lk];
                b4[f] = *(const f16x8*)&sVt[(f * 16 + lr) * 72 + ks * 32 + lk];
            }
#pragma unroll
            for (int fm = 0; fm < 4; fm++)
#pragma unroll
                for (int fn = 0; fn < 4; fn++)
                    akv[fm][fn] = mfma16h(a4[fm], b4[fn], akv[fm][fn]);
        }
    }
    // owned-slab stores (no atomics)
    const size_t base = ((size_t)(kc * 64 + bh)) << 14;
#pragma unroll
    for (int fm = 0; fm < 4; fm++)
#pragma unroll
        for (int fn = 0; fn < 4; fn++)
#pragma unroll
            for (int r = 0; r < 4; r++) {
                int m = wave * 64 + fm * 16 + (lane >> 4) * 4 + r;
                int d = fn * 16 + lr;
                KVacc[base + m * 64 + d] = akv[fm][fn][r];
            }
#pragma unroll
    for (int fn = 0; fn < 4; fn++) {
        ksm[fn] += __shfl_xor(ksm[fn], 16);
        ksm[fn] += __shfl_xor(ksm[fn], 32);
    }
    if (lane < 16) {
#pragma unroll
        for (int fn = 0; fn < 4; fn++)
            Ksum[(kc * 64 + bh) * 256 + wave * 64 + fn * 16 + lane] = ksm[fn];
    }
}

// ---------------- slab reduce: KVt[bh][d][m] = fp16(sum_kc KVacc), KsumR = sum_kc Ksum ----------------
__global__ __launch_bounds__(256) void k_kvt(const float* __restrict__ KVacc,
                                             const float* __restrict__ Ksum,
                                             u16* __restrict__ KVt, float* __restrict__ KsumR) {
    int i = blockIdx.x * 256 + threadIdx.x;
    if (blockIdx.x < 16384) {
        int bh = i >> 14, m = (i >> 6) & 255, d = i & 63;
        float s = 0.f;
#pragma unroll
        for (int kc = 0; kc < 8; kc++)
            s += KVacc[(((size_t)(kc * 64 + bh)) << 14) + m * 64 + d];
        KVt[((size_t)bh << 14) + d * 256 + m] = f2h(s);
    } else {
        int j = i - 4194304; // bh*256+m, 16384 total
        int bh = j >> 8, m = j & 255;
        float s = 0.f;
#pragma unroll
        for (int kc = 0; kc < 8; kc++)
            s += Ksum[(kc * 64 + bh) * 256 + m];
        KsumR[j] = s;
    }
}

// ---------------- fused phi(Q) + norm + attn: 4 subtiles/block, Q prefetch ----------------
__global__ __launch_bounds__(512) void k_phiq_attn(
    const u16* __restrict__ QK, const u16* __restrict__ wt,
    const u16* __restrict__ KVt, const float* __restrict__ Ksum,
    u16* __restrict__ attn) {
    __shared__ __align__(16) u16 sQh[64 * 72];
    __shared__ __align__(16) u16 sQf[64 * 264];
    __shared__ float sKs[256];
    __shared__ float snsq[64];
    __shared__ float snorm[64];
    const int tid = threadIdx.x, wave = tid >> 6, lane = tid & 63;
    const int lr = lane & 15, lk = (lane >> 4) * 8;
    const int bh = blockIdx.y, b = bh >> 4, h = bh & 15;
    const int mq = wave & 3;
    const int lh = wave >> 2;
    const int af = wave & 3;
    const int ad = wave >> 2;

    f16x8 wb[4][2];
#pragma unroll
    for (int fn = 0; fn < 4; fn++)
#pragma unroll
        for (int ks = 0; ks < 2; ks++)
            wb[fn][ks] = *(const f16x8*)(wt + (size_t)(mq * 64 + fn * 16 + lr) * 64 + ks * 32 + lk);
    f16x8 kvb[2][8];
#pragma unroll
    for (int fn = 0; fn < 2; fn++)
#pragma unroll
        for (int ks = 0; ks < 8; ks++)
            kvb[fn][ks] = *(const f16x8*)(KVt + ((size_t)bh << 14) +
                                          (size_t)(ad * 32 + fn * 16 + lr) * 256 + ks * 32 + lk);
    if (tid < 256) sKs[tid] = Ksum[bh * 256 + tid];

    // Q prefetch for st=0
    const int rowQ = tid >> 3, cQ = (tid & 7) * 8;
    size_t gQ = ((size_t)(b * Ll + blockIdx.x * 256 + rowQ)) * 2048 + h * 64 + cQ;
    u16x8 vh = *(const u16x8*)(QK + gQ);

    for (int st = 0; st < 4; st++) {
        const int l0 = blockIdx.x * 256 + st * 64;
        __syncthreads();
        { // stage Q + nsq from regs
            *(u16x8*)&sQh[rowQ * 72 + cQ] = vh;
            float s = 0.f;
#pragma unroll
            for (int j = 0; j < 8; j++) { float a = h2f(vh[j]); s += a * a; }
            s += __shfl_xor(s, 1); s += __shfl_xor(s, 2); s += __shfl_xor(s, 4);
            if ((tid & 7) == 0) snsq[rowQ] = s * 0.0625f;
        }
        __syncthreads();
#pragma unroll
        for (int fm = 0; fm < 2; fm++) {
            f32x4 ap[4];
#pragma unroll
            for (int fn = 0; fn < 4; fn++)
#pragma unroll
                for (int r = 0; r < 4; r++) ap[fn][r] = 0.f;
#pragma unroll
            for (int ks = 0; ks < 2; ks++) {
                f16x8 aH = *(const f16x8*)&sQh[(lh * 32 + fm * 16 + lr) * 72 + ks * 32 + lk];
#pragma unroll
                for (int fn = 0; fn < 4; fn++)
                    ap[fn] = mfma16h(aH, wb[fn][ks], ap[fn]);
            }
#pragma unroll
            for (int fn = 0; fn < 4; fn++)
#pragma unroll
                for (int r = 0; r < 4; r++) {
                    int l = lh * 32 + fm * 16 + (lane >> 4) * 4 + r;
                    int m = mq * 64 + fn * 16 + lr;
                    sQf[l * 264 + m] = f2h(__expf(ap[fn][r] - snsq[l]) * 0.0625f);
                }
        }
        if (st < 3) { // issue next Q load; lands under norm+attn+epilogue
            gQ += 131072;
            vh = *(const u16x8*)(QK + gQ);
        }
        __syncthreads();
        { // norm
            int l = tid >> 3, m0 = (tid & 7) * 32;
            float s = 0.f;
#pragma unroll
            for (int j4 = 0; j4 < 4; j4++) {
                u16x8 qv = *(const u16x8*)&sQf[l * 264 + m0 + j4 * 8];
#pragma unroll
                for (int j = 0; j < 8; j++) s += h2f(qv[j]) * sKs[m0 + j4 * 8 + j];
            }
            s += __shfl_xor(s, 1); s += __shfl_xor(s, 2); s += __shfl_xor(s, 4);
            if ((tid & 7) == 0) snorm[l] = s;
        }
        f32x4 aa[2];
#pragma unroll
        for (int fn = 0; fn < 2; fn++)
#pragma unroll
            for (int r = 0; r < 4; r++) aa[fn][r] = 0.f;
#pragma unroll
        for (int ks = 0; ks < 8; ks++) {
            f16x8 a = *(const f16x8*)&sQf[(af * 16 + lr) * 264 + ks * 32 + lk];
            aa[0] = mfma16h(a, kvb[0][ks], aa[0]);
            aa[1] = mfma16h(a, kvb[1][ks], aa[1]);
        }
        __syncthreads();
        float* ep = (float*)sQf; // [64][68]
#pragma unroll
        for (int fn = 0; fn < 2; fn++)
#pragma unroll
            for (int r = 0; r < 4; r++) {
                int l = af * 16 + (lane >> 4) * 4 + r;
                int d = ad * 32 + fn * 16 + lr;
                ep[l * 68 + d] = aa[fn][r];
            }
        __syncthreads();
        {
            int l = tid >> 3, d0 = (tid & 7) * 8;
            float inv = 1.0f / fmaxf(snorm[l], 6.25e-8f);
            u16x8 o;
#pragma unroll
            for (int j = 0; j < 8; j++) o[j] = f2h(ep[l * 68 + d0 + j] * inv);
            *(u16x8*)(attn + ((size_t)(b * Ll + l0 + l)) * 1024 + h * 64 + d0) = o;
        }
    }
}

extern "C" void kernel_launch(void* const* d_in, const int* in_sizes, int n_in,
                              void* d_out, int out_size, void* d_ws, size_t ws_size,
                              hipStream_t stream) {
    (void)in_sizes; (void)n_in; (void)out_size; (void)ws_size;
    const float* x  = (const float*)d_in[0];
    const float* Wq = (const float*)d_in[1];
    const float* Wk = (const float*)d_in[2];
    const float* Wv = (const float*)d_in[3];
    const float* Wo = (const float*)d_in[4];
    const float* bo = (const float*)d_in[5];
    const float* om = (const float*)d_in[6];

    char* w = (char*)d_ws;
    size_t o = 0;
    auto take = [&](size_t n) { char* p = w + o; o += n; return p; };
    u16* QK  = (u16*)take(67108864);   // [16384][2048] fp16: Q | K
    u16* Vb  = (u16*)take(33554432);   // [16384][1024] fp16
    u16* xh  = (u16*)take(33554432);   // x fp16
    u16* Wc  = (u16*)take(8388608);    // Wq|Wk|Wv|Wo fp16 [4096][1024]
    u16* wt  = (u16*)take(32768);      // omega^T scaled fp16 [256][64]
    float* KVacc = (float*)take(33554432); // 8 slabs x [64 bh][256 m][64 d]
    float* Ksum  = (float*)take(524288);   // 8 slabs x [64 bh][256 m]
    float* KsumR = (float*)take(65536);    // [64 bh][256 m]
    u16* KVt = (u16*)take(2097152);        // [64 bh][64 d][256 m]
    u16* Wof  = Wc + 3145728;
    u16* attn = Vb; // alias: V dead after k_phik_kv

    k_prep<<<20544, 256, 0, stream>>>(x, Wq, Wk, Wv, Wo, om, xh, Wc, wt);
    k_gemm_qkv<<<dim3(12, 64), 512, 0, stream>>>(xh, Wc, QK, Vb);
    k_phik_kv<<<dim3(8, 64), 256, 0, stream>>>(QK, wt, Vb, KVacc, Ksum);
    k_kvt<<<16448, 256, 0, stream>>>(KVacc, Ksum, KVt, KsumR);
    k_phiq_attn<<<dim3(16, 64), 512, 0, stream>>>(QK, wt, KVt, KsumR, attn);
    k_gemm_out<<<dim3(4, 64), 512, 0, stream>>>(attn, Wof, bo, (float*)d_out);
}